// Round 12
// baseline (724.976 us; speedup 1.0000x reference)
//
#include <hip/hip_runtime.h>
#include <hip/hip_bf16.h>

#define HD 128
#define SCB 2048   // elements per scan block

typedef __attribute__((ext_vector_type(8))) short short8v;
typedef __attribute__((ext_vector_type(4))) float f32x4;
typedef unsigned short us;

__device__ __forceinline__ us f2bf(float f) {
    union { float f; unsigned u; } c; c.f = f;
    unsigned u = c.u;
    return (us)((u + 0x7fffu + ((u >> 16) & 1u)) >> 16);
}
__device__ __forceinline__ float bf2f(us b) {
    union { unsigned u; float f; } c; c.u = ((unsigned)b) << 16;
    return c.f;
}

// async global->LDS, 16B per lane; LDS dest must be wave-uniform base + lane*16
__device__ __forceinline__ void gload16(const void* g, void* l) {
    __builtin_amdgcn_global_load_lds(
        (const __attribute__((address_space(1))) unsigned int*)g,
        (__attribute__((address_space(3))) unsigned int*)l,
        16, 0, 0);
}

// ---------------------------------------------------------------------------
// MFMA node GEMM, fp32 via bf16 hi/lo split (3 MFMA per logical fp32 term).
// Block: 512 threads = 8 waves; tile 64 rows x 128 cols (wave = 64r x 16c).
// A staged via global_load_lds: LINEAR LDS dest + pre-swizzled global source
// (byte (c*16)^((row&7)<<4)); compute reads use the same XOR (involution).
// B (weights, [col][K]) in registers per wave (L2-hot).
// ---------------------------------------------------------------------------
template<int KSTEPS, int K1S, bool HASA2, bool RELU, bool DEGB, bool WF32, bool WBF>
__global__ __launch_bounds__(512) void k_mgemm(
    const us* __restrict__ A1h, const us* __restrict__ A1l,
    const us* __restrict__ A2h, const us* __restrict__ A2l,
    const us* __restrict__ Wth, const us* __restrict__ Wtl,
    const float* __restrict__ bias,
    const float* __restrict__ bdeg, const float* __restrict__ deg,
    float* __restrict__ Cf0, float* __restrict__ Cf1,
    us* __restrict__ Ch, us* __restrict__ Cl,
    int nrows)
{
    constexpr int K   = KSTEPS * 32;
    constexpr int CPR = K / 8;              // 16B chunks per row
    constexpr int ITER = (64 * CPR) / 512;  // staging chunks per thread
    __shared__ us As_h[64 * K];
    __shared__ us As_l[64 * K];

    const int tid  = threadIdx.x;
    const int wv   = tid >> 6;
    const int lane = tid & 63;
    const int r    = lane & 15;
    const int g    = lane >> 4;
    const int rb   = blockIdx.x * 64;
    const int col  = blockIdx.y * 128 + wv * 16 + r;

    short8v bh[KSTEPS], bl[KSTEPS];
    {
        size_t wbase = (size_t)col * K + (size_t)(g * 8);
#pragma unroll
        for (int s = 0; s < KSTEPS; ++s) {
            bh[s] = *(const short8v*)(Wth + wbase + s * 32);
            bl[s] = *(const short8v*)(Wtl + wbase + s * 32);
        }
    }

    // ---- stage A: linear LDS dest, swizzled global source ----
#pragma unroll
    for (int i = 0; i < ITER; ++i) {
        int f = tid + i * 512;
        int row = f / CPR, c = f % CPR;
        int grow = rb + row; if (grow >= nrows) grow = nrows - 1;
        int sb = (c * 16) ^ ((row & 7) << 4);   // source byte within row
        const char *gh, *gl;
        if (!HASA2 || sb < K1S * 2) {
            gh = (const char*)A1h + (size_t)grow * (K1S * 2) + sb;
            gl = (const char*)A1l + (size_t)grow * (K1S * 2) + sb;
        } else {
            gh = (const char*)A2h + (size_t)grow * ((K - K1S) * 2) + (sb - K1S * 2);
            gl = (const char*)A2l + (size_t)grow * ((K - K1S) * 2) + (sb - K1S * 2);
        }
        gload16(gh, (char*)As_h + (size_t)f * 16);
        gload16(gl, (char*)As_l + (size_t)f * 16);
    }
    __syncthreads();

    f32x4 acc[4];
#pragma unroll
    for (int t = 0; t < 4; ++t) acc[t] = (f32x4){0.f, 0.f, 0.f, 0.f};

#pragma unroll
    for (int s = 0; s < KSTEPS; ++s) {
#pragma unroll
        for (int t = 0; t < 4; ++t) {
            int row = t * 16 + r;
            int boff = row * (K * 2) + (((s * 64) + g * 16) ^ ((row & 7) << 4));
            short8v ah = *(const short8v*)((const char*)As_h + boff);
            short8v al = *(const short8v*)((const char*)As_l + boff);
            acc[t] = __builtin_amdgcn_mfma_f32_16x16x32_bf16(ah, bh[s], acc[t], 0, 0, 0);
            acc[t] = __builtin_amdgcn_mfma_f32_16x16x32_bf16(al, bh[s], acc[t], 0, 0, 0);
            acc[t] = __builtin_amdgcn_mfma_f32_16x16x32_bf16(ah, bl[s], acc[t], 0, 0, 0);
        }
    }

    const float bb = (bias && col < 128) ? bias[col] : 0.f;
    const float bd = (DEGB && col < 128) ? bdeg[col] : 0.f;
    const int jc = col & 127;
#pragma unroll
    for (int t = 0; t < 4; ++t) {
#pragma unroll
        for (int i = 0; i < 4; ++i) {
            int row = rb + t * 16 + g * 4 + i;
            if (row >= nrows) continue;
            float v = acc[t][i] + bb;
            if (DEGB) v += deg[row] * bd;
            if (RELU) v = fmaxf(v, 0.f);
            size_t o = (size_t)row * HD + jc;
            if (WF32) (col < 128 ? Cf0 : Cf1)[o] = v;
            if (WBF) {
                us hh = f2bf(v);
                Ch[o] = hh;
                Cl[o] = f2bf(v - bf2f(hh));
            }
        }
    }
}

// ---------------------------------------------------------------------------
// Fused update: U = relu([h|S]@Wcb + b1 + deg*bdeg) ; hout = relu(U@U2 + b2).
// Stage-1 A staged via global_load_lds (swizzled source); U-tile written back
// into the A LDS (barrier-guarded) for stage 2.
// ---------------------------------------------------------------------------
__global__ __launch_bounds__(512) void k_upd(
    const us* __restrict__ A1h, const us* __restrict__ A1l,
    const us* __restrict__ A2h, const us* __restrict__ A2l,
    const us* __restrict__ Wth, const us* __restrict__ Wtl,   // [128 j][256 k]
    const float* __restrict__ b1,
    const float* __restrict__ bdeg, const float* __restrict__ deg,
    const us* __restrict__ W2th, const us* __restrict__ W2tl, // [128 j][128 k]
    const float* __restrict__ b2,
    us* __restrict__ out_h, us* __restrict__ out_l,
    int nrows)
{
    constexpr int K = 256;
    constexpr int CPR = K / 8;
    constexpr int ITER = (64 * CPR) / 512;
    __shared__ us As_h[64 * K];
    __shared__ us As_l[64 * K];

    const int tid  = threadIdx.x;
    const int wv   = tid >> 6;
    const int lane = tid & 63;
    const int r    = lane & 15;
    const int g    = lane >> 4;
    const int rb   = blockIdx.x * 64;
    const int col  = wv * 16 + r;

    short8v bh[8], bl[8];
    {
        size_t wbase = (size_t)col * K + (size_t)(g * 8);
#pragma unroll
        for (int s = 0; s < 8; ++s) {
            bh[s] = *(const short8v*)(Wth + wbase + s * 32);
            bl[s] = *(const short8v*)(Wtl + wbase + s * 32);
        }
    }

    // stage A = [h|S] (each row: 256B of h, 256B of S), swizzled source
#pragma unroll
    for (int i = 0; i < ITER; ++i) {
        int f = tid + i * 512;
        int row = f / CPR, c = f % CPR;
        int grow = rb + row; if (grow >= nrows) grow = nrows - 1;
        int sb = (c * 16) ^ ((row & 7) << 4);
        const char *gh, *gl;
        if (sb < 256) {
            gh = (const char*)A1h + (size_t)grow * 256 + sb;
            gl = (const char*)A1l + (size_t)grow * 256 + sb;
        } else {
            gh = (const char*)A2h + (size_t)grow * 256 + (sb - 256);
            gl = (const char*)A2l + (size_t)grow * 256 + (sb - 256);
        }
        gload16(gh, (char*)As_h + (size_t)f * 16);
        gload16(gl, (char*)As_l + (size_t)f * 16);
    }
    __syncthreads();

    f32x4 acc[4];
#pragma unroll
    for (int t = 0; t < 4; ++t) acc[t] = (f32x4){0.f, 0.f, 0.f, 0.f};
#pragma unroll
    for (int s = 0; s < 8; ++s) {
#pragma unroll
        for (int t = 0; t < 4; ++t) {
            int row = t * 16 + r;
            int boff = row * (K * 2) + (((s * 64) + g * 16) ^ ((row & 7) << 4));
            short8v ah = *(const short8v*)((const char*)As_h + boff);
            short8v al = *(const short8v*)((const char*)As_l + boff);
            acc[t] = __builtin_amdgcn_mfma_f32_16x16x32_bf16(ah, bh[s], acc[t], 0, 0, 0);
            acc[t] = __builtin_amdgcn_mfma_f32_16x16x32_bf16(al, bh[s], acc[t], 0, 0, 0);
            acc[t] = __builtin_amdgcn_mfma_f32_16x16x32_bf16(ah, bl[s], acc[t], 0, 0, 0);
        }
    }
    __syncthreads();   // all As reads complete; safe to overwrite with U tile

    short8v b2h[4], b2l[4];
    {
        size_t wbase = (size_t)col * 128 + (size_t)(g * 8);
#pragma unroll
        for (int s = 0; s < 4; ++s) {
            b2h[s] = *(const short8v*)(W2th + wbase + s * 32);
            b2l[s] = *(const short8v*)(W2tl + wbase + s * 32);
        }
    }

    {
        const float bb = b1[col];
        const float bd = bdeg[col];
#pragma unroll
        for (int t = 0; t < 4; ++t) {
#pragma unroll
            for (int i = 0; i < 4; ++i) {
                int lrow = t * 16 + g * 4 + i;
                int grow = rb + lrow;
                float dg = (grow < nrows) ? deg[grow] : 0.f;
                float v = acc[t][i] + bb + dg * bd;
                v = fmaxf(v, 0.f);
                us uh = f2bf(v);
                us ul = f2bf(v - bf2f(uh));
                int byte = lrow * 256 + ((col * 2) ^ ((lrow & 7) << 4));
                *(us*)((char*)As_h + byte) = uh;
                *(us*)((char*)As_l + byte) = ul;
            }
        }
    }
    __syncthreads();

    f32x4 acc2[4];
#pragma unroll
    for (int t = 0; t < 4; ++t) acc2[t] = (f32x4){0.f, 0.f, 0.f, 0.f};
#pragma unroll
    for (int s = 0; s < 4; ++s) {
#pragma unroll
        for (int t = 0; t < 4; ++t) {
            int row = t * 16 + r;
            int boff = row * 256 + (((s * 64) + g * 16) ^ ((row & 7) << 4));
            short8v ah = *(const short8v*)((const char*)As_h + boff);
            short8v al = *(const short8v*)((const char*)As_l + boff);
            acc2[t] = __builtin_amdgcn_mfma_f32_16x16x32_bf16(ah, b2h[s], acc2[t], 0, 0, 0);
            acc2[t] = __builtin_amdgcn_mfma_f32_16x16x32_bf16(al, b2h[s], acc2[t], 0, 0, 0);
            acc2[t] = __builtin_amdgcn_mfma_f32_16x16x32_bf16(ah, b2l[s], acc2[t], 0, 0, 0);
        }
    }
    const float bb2 = b2[col];
#pragma unroll
    for (int t = 0; t < 4; ++t) {
#pragma unroll
        for (int i = 0; i < 4; ++i) {
            int row = rb + t * 16 + g * 4 + i;
            if (row >= nrows) continue;
            float v = fmaxf(acc2[t][i] + bb2, 0.f);
            size_t o = (size_t)row * HD + col;
            us hh = f2bf(v);
            out_h[o] = hh;
            out_l[o] = f2bf(v - bf2f(hh));
        }
    }
}

// ---------------------------------------------------------------------------
// Conversions
// ---------------------------------------------------------------------------
__global__ void k_cvtA(const float* __restrict__ src,
                       us* __restrict__ dh, us* __restrict__ dl, long n)
{
    long i = (long)blockIdx.x * blockDim.x + threadIdx.x;
    if (i >= n) return;
    float v = src[i];
    us h = f2bf(v);
    dh[i] = h;
    dl[i] = f2bf(v - bf2f(h));
}

__global__ void k_cvtW(const float* __restrict__ src, long sstride, int K,
                       us* __restrict__ dh, us* __restrict__ dl, long dstride)
{
    int l = blockIdx.y;
    int idx = blockIdx.x * 256 + threadIdx.x;
    if (idx >= K * 128) return;
    int k = idx >> 7, j = idx & 127;
    float v = src[(size_t)l * sstride + (size_t)k * 128 + j];
    us h = f2bf(v);
    size_t o = (size_t)l * dstride + (size_t)j * K + k;
    dh[o] = h;
    dl[o] = f2bf(v - bf2f(h));
}

__global__ void k_cvtW2(const float* __restrict__ srcA, long strideA,
                        const float* __restrict__ srcB, long strideB,
                        int K1s, int K,
                        us* __restrict__ dh, us* __restrict__ dl, long dstride)
{
    int l = blockIdx.y;
    int idx = blockIdx.x * 256 + threadIdx.x;
    if (idx >= K * 128) return;
    int k = idx >> 7, j = idx & 127;
    float v = (k < K1s)
        ? srcA[(size_t)l * strideA + (size_t)k * 128 + j]
        : srcB[(size_t)l * strideB + (size_t)(k - K1s) * 128 + j];
    us h = f2bf(v);
    size_t o = (size_t)l * dstride + (size_t)j * K + k;
    dh[o] = h;
    dl[o] = f2bf(v - bf2f(h));
}

// ---------------------------------------------------------------------------
// CSR build: deg+hist -> 3-phase parallel scan -> scatter (fused ea permute)
// ---------------------------------------------------------------------------
__global__ void k_deghist(const int* __restrict__ dst, int* __restrict__ degi, int E,
                          const int* __restrict__ batch, int* __restrict__ gcnt, int N)
{
    int i = blockIdx.x * blockDim.x + threadIdx.x;
    if (i < E) atomicAdd(&degi[dst[i]], 1);
    if (i < N) atomicAdd(&gcnt[batch[i]], 1);
}

__global__ __launch_bounds__(256) void k_scan1(const int* __restrict__ degi,
                                               int* __restrict__ thrpre,
                                               int* __restrict__ bsum, int N)
{
    __shared__ int sc[256];
    const int t = threadIdx.x, b = blockIdx.x;
    int i0 = b * SCB + t * 8;
    int s = 0;
#pragma unroll
    for (int q = 0; q < 8; ++q) {
        int i = i0 + q;
        if (i < N) s += degi[i];
    }
    sc[t] = s;
    __syncthreads();
    for (int o = 1; o < 256; o <<= 1) {
        int v = (t >= o) ? sc[t - o] : 0;
        __syncthreads();
        sc[t] += v;
        __syncthreads();
    }
    thrpre[b * 256 + t] = sc[t] - s;
    if (t == 255) bsum[b] = sc[255];
}

__global__ void k_scan2(const int* __restrict__ bsum, int* __restrict__ boff, int nb)
{
    if (threadIdx.x == 0 && blockIdx.x == 0) {
        int run = 0;
        for (int b = 0; b < nb; ++b) { boff[b] = run; run += bsum[b]; }
    }
}

__global__ __launch_bounds__(256) void k_scan3(
    const int* __restrict__ degi, const int* __restrict__ thrpre,
    const int* __restrict__ boff,
    int* __restrict__ rowptr, int* __restrict__ cursor,
    float* __restrict__ degf, int N, int E)
{
    const int t = threadIdx.x, b = blockIdx.x;
    int run = boff[b] + thrpre[b * 256 + t];
    int i0 = b * SCB + t * 8;
#pragma unroll
    for (int q = 0; q < 8; ++q) {
        int i = i0 + q;
        if (i < N) {
            int d = degi[i];
            rowptr[i] = run;
            cursor[i] = run;
            degf[i] = (float)d;
            run += d;
        }
    }
    if (b == 0 && t == 0) rowptr[N] = E;
}

__global__ void k_scatter(const int* __restrict__ dst, const int* __restrict__ src,
                          int* __restrict__ cursor,
                          const float* __restrict__ ea,
                          int* __restrict__ csr_src, int* __restrict__ csr_eid,
                          float* __restrict__ ea_p, int E)
{
    int e = blockIdx.x * blockDim.x + threadIdx.x;
    if (e >= E) return;
    int d = dst[e];
    int pos = atomicAdd(&cursor[d], 1);
    csr_src[pos] = src[e];
    if (ea_p) {
        const float4* s4 = (const float4*)&ea[(size_t)e * 16];
        float4* d4 = (float4*)&ea_p[(size_t)pos * 16];
        d4[0] = s4[0]; d4[1] = s4[1]; d4[2] = s4[2]; d4[3] = s4[3];
    } else {
        csr_eid[pos] = e;
    }
}

// ---------------------------------------------------------------------------
// Weight folds: fold = W2 @ U1b ; bvec2 = b2 @ U1b
// ---------------------------------------------------------------------------
__global__ __launch_bounds__(256) void k_foldW(
    const float* __restrict__ msg_W2, const float* __restrict__ upd_W1,
    float* __restrict__ fold)
{
    int l = blockIdx.x >> 3, rb = blockIdx.x & 7;
    const float* W2  = msg_W2 + (size_t)l * HD * HD;
    const float* U1b = upd_W1 + (size_t)l * 256 * HD + (size_t)HD * HD;
    float* Wout = fold + (size_t)l * HD * HD;
    int j = threadIdx.x & 127;
    int rh = threadIdx.x >> 7;
    int r0 = rb * 16 + rh * 8;
    float acc[8] = {0.f,0.f,0.f,0.f,0.f,0.f,0.f,0.f};
    for (int k = 0; k < HD; ++k) {
        float u = U1b[(size_t)k * HD + j];
#pragma unroll
        for (int rr = 0; rr < 8; ++rr)
            acc[rr] = fmaf(W2[(size_t)(r0 + rr) * HD + k], u, acc[rr]);
    }
#pragma unroll
    for (int rr = 0; rr < 8; ++rr)
        Wout[(size_t)(r0 + rr) * HD + j] = acc[rr];
}

__global__ __launch_bounds__(128) void k_foldb(
    const float* __restrict__ msg_b2, const float* __restrict__ upd_W1,
    float* __restrict__ bvec2)
{
    int l = blockIdx.x, j = threadIdx.x;
    const float* U1b = upd_W1 + (size_t)l * 256 * HD + (size_t)HD * HD;
    const float* b2 = msg_b2 + (size_t)l * HD;
    float acc = 0.f;
    for (int k = 0; k < HD; ++k) acc = fmaf(b2[k], U1b[(size_t)k * HD + j], acc);
    bvec2[(size_t)l * HD + j] = acc;
}

// ---------------------------------------------------------------------------
// Edge gather: S[n] = sum_{e:dst=n} relu(P[n] + Q[src] + ea@Wc)
// Fixed grid; each wave owns a CONTIGUOUS chunk of nodes (sum-of-degrees
// balances by CLT, removing the max-of-4-singletons block-retire tail).
// Per node: 16-edge clamped batch; indices via coalesced load + readlane.
// ---------------------------------------------------------------------------
#define EB 16
template<bool PERM>
__global__ __launch_bounds__(256) void k_edge(
    const float* __restrict__ P, const float* __restrict__ Q,
    const float* __restrict__ EA,
    const int* __restrict__ rowptr,
    const int* __restrict__ csr_src, const int* __restrict__ csr_eid,
    const float* __restrict__ W1c,
    us* __restrict__ Sh, us* __restrict__ Sl, int N, int chunk)
{
    const int lane = threadIdx.x & 63;
    const int wid  = blockIdx.x * 4 + (threadIdx.x >> 6);
    int n0 = wid * chunk;
    int n1 = n0 + chunk; if (n1 > N) n1 = N;
    if (n0 >= N) return;

    float wA[16], wB[16];
#pragma unroll
    for (int k = 0; k < 16; ++k) {
        wA[k] = W1c[k * HD + lane];
        wB[k] = W1c[k * HD + 64 + lane];
    }

    for (int node = n0; node < n1; ++node) {
        const int beg = __builtin_amdgcn_readfirstlane(rowptr[node]);
        const int end = __builtin_amdgcn_readfirstlane(rowptr[node + 1]);
        const float pA = P[(size_t)node * HD + lane];
        const float pB = P[(size_t)node * HD + 64 + lane];
        float accA = 0.f, accB = 0.f;

        for (int i = beg; i < end; i += EB) {
            int myi = i + (lane & 15);
            myi = (myi < end) ? myi : (end - 1);
            int myidx = PERM ? myi : csr_eid[myi];
            int mysrc = csr_src[myi];
            int sv[EB], ei[EB];
#pragma unroll
            for (int r = 0; r < EB; ++r) {
                sv[r] = __builtin_amdgcn_readlane(mysrc, r);
                ei[r] = PERM ? 0 : __builtin_amdgcn_readlane(myidx, r);
            }
            float qA[EB], qB[EB];
#pragma unroll
            for (int r = 0; r < EB; ++r) {
                qA[r] = Q[(size_t)sv[r] * HD + lane];
                qB[r] = Q[(size_t)sv[r] * HD + 64 + lane];
            }
#pragma unroll
            for (int r = 0; r < EB; ++r) {
                int ii = i + r; ii = (ii < end) ? ii : (end - 1);
                const float4* Ev = PERM ? (const float4*)&EA[(size_t)ii * 16]
                                        : (const float4*)&EA[(size_t)ei[r] * 16];
                float4 v0 = Ev[0], v1 = Ev[1], v2 = Ev[2], v3 = Ev[3];
                float tA = pA + qA[r], tB = pB + qB[r];
                tA = fmaf(v0.x, wA[0],  tA); tB = fmaf(v0.x, wB[0],  tB);
                tA = fmaf(v0.y, wA[1],  tA); tB = fmaf(v0.y, wB[1],  tB);
                tA = fmaf(v0.z, wA[2],  tA); tB = fmaf(v0.z, wB[2],  tB);
                tA = fmaf(v0.w, wA[3],  tA); tB = fmaf(v0.w, wB[3],  tB);
                tA = fmaf(v1.x, wA[4],  tA); tB = fmaf(v1.x, wB[4],  tB);
                tA = fmaf(v1.y, wA[5],  tA); tB = fmaf(v1.y, wB[5],  tB);
                tA = fmaf(v1.z, wA[6],  tA); tB = fmaf(v1.z, wB[6],  tB);
                tA = fmaf(v1.w, wA[7],  tA); tB = fmaf(v1.w, wB[7],  tB);
                tA = fmaf(v2.x, wA[8],  tA); tB = fmaf(v2.x, wB[8],  tB);
                tA = fmaf(v2.y, wA[9],  tA); tB = fmaf(v2.y, wB[9],  tB);
                tA = fmaf(v2.z, wA[10], tA); tB = fmaf(v2.z, wB[10], tB);
                tA = fmaf(v2.w, wA[11], tA); tB = fmaf(v2.w, wB[11], tB);
                tA = fmaf(v3.x, wA[12], tA); tB = fmaf(v3.x, wB[12], tB);
                tA = fmaf(v3.y, wA[13], tA); tB = fmaf(v3.y, wB[13], tB);
                tA = fmaf(v3.z, wA[14], tA); tB = fmaf(v3.z, wB[14], tB);
                tA = fmaf(v3.w, wA[15], tA); tB = fmaf(v3.w, wB[15], tB);
                bool ok = (i + r) < end;
                accA += ok ? fmaxf(tA, 0.f) : 0.f;
                accB += ok ? fmaxf(tB, 0.f) : 0.f;
            }
        }
        size_t oA = (size_t)node * HD + lane;
        size_t oB = oA + 64;
        us hA = f2bf(accA);
        us hB = f2bf(accB);
        Sh[oA] = hA; Sl[oA] = f2bf(accA - bf2f(hA));
        Sh[oB] = hB; Sl[oB] = f2bf(accB - bf2f(hB));
    }
}

// ---------------------------------------------------------------------------
// Pool (segment mean/max over sorted batch) from bf16 hi/lo h; then classifier.
// ---------------------------------------------------------------------------
__global__ __launch_bounds__(256) void k_pool2(
    const us* __restrict__ hh, const us* __restrict__ hl,
    const int* __restrict__ batch,
    float* __restrict__ gsum, unsigned int* __restrict__ gmax, int N)
{
    int nchunk = (N + gridDim.x - 1) / gridDim.x;
    int n0 = blockIdx.x * nchunk;
    int n1 = n0 + nchunk; if (n1 > N) n1 = N;
    int j = threadIdx.x & 127;
    int half = threadIdx.x >> 7;
    float s = 0.f, m = 0.f; int gcur = -1;
    for (int n = n0 + half; n < n1; n += 2) {
        int g = batch[n];
        if (g != gcur) {
            if (gcur >= 0) {
                atomicAdd(&gsum[(size_t)gcur * HD + j], s);
                atomicMax(&gmax[(size_t)gcur * HD + j], __float_as_uint(m));
            }
            gcur = g; s = 0.f; m = 0.f;
        }
        size_t o = (size_t)n * HD + j;
        float v = bf2f(hh[o]) + bf2f(hl[o]);
        s += v; m = fmaxf(m, v);
    }
    if (gcur >= 0) {
        atomicAdd(&gsum[(size_t)gcur * HD + j], s);
        atomicMax(&gmax[(size_t)gcur * HD + j], __float_as_uint(m));
    }
}

__global__ __launch_bounds__(128) void k_cls(
    const float* __restrict__ gsum, const float* __restrict__ gmax,
    const int* __restrict__ gcnt,
    const float* __restrict__ W1, const float* __restrict__ b1,
    const float* __restrict__ W2, const float* __restrict__ b2,
    const float* __restrict__ W3, const float* __restrict__ b3,
    float* __restrict__ out)
{
    __shared__ float rep[256];
    __shared__ float z1[128];
    __shared__ float z2[64];
    const int g = blockIdx.x;
    const int j = threadIdx.x;
    float cntf = (float)gcnt[g];
    rep[j]       = gsum[(size_t)g * HD + j] / fmaxf(cntf, 1.f);
    rep[128 + j] = gmax[(size_t)g * HD + j];
    __syncthreads();
    float a = 0.f;
    for (int k = 0; k < 256; ++k) a = fmaf(rep[k], W1[(size_t)k * 128 + j], a);
    z1[j] = fmaxf(a + b1[j], 0.f);
    __syncthreads();
    if (j < 64) {
        float b = 0.f;
        for (int k = 0; k < 128; ++k) b = fmaf(z1[k], W2[(size_t)k * 64 + j], b);
        z2[j] = fmaxf(b + b2[j], 0.f);
    }
    __syncthreads();
    if (j < 2) {
        float c = 0.f;
        for (int k = 0; k < 64; ++k) c = fmaf(z2[k], W3[(size_t)k * 2 + j], c);
        out[(size_t)g * 2 + j] = c + b3[j];
    }
}

extern "C" void kernel_launch(void* const* d_in, const int* in_sizes, int n_in,
                              void* d_out, int out_size, void* d_ws, size_t ws_size,
                              hipStream_t stream) {
    const float* x      = (const float*)d_in[0];
    const float* ea     = (const float*)d_in[1];
    const int*   ei     = (const int*)d_in[2];
    const int*   batch  = (const int*)d_in[3];
    const float* emb_W  = (const float*)d_in[4];
    const float* emb_b  = (const float*)d_in[5];
    const float* msg_W1 = (const float*)d_in[6];
    const float* msg_b1 = (const float*)d_in[7];
    const float* msg_W2 = (const float*)d_in[8];
    const float* msg_b2 = (const float*)d_in[9];
    const float* upd_W1 = (const float*)d_in[10];
    const float* upd_b1 = (const float*)d_in[11];
    const float* upd_W2 = (const float*)d_in[12];
    const float* upd_b2 = (const float*)d_in[13];
    const float* cW1 = (const float*)d_in[14];
    const float* cb1 = (const float*)d_in[15];
    const float* cW2 = (const float*)d_in[16];
    const float* cb2 = (const float*)d_in[17];
    const float* cW3 = (const float*)d_in[18];
    const float* cb3 = (const float*)d_in[19];

    const int N = in_sizes[0] / 64;
    const int E = in_sizes[1] / 16;
    const int G = 256, L = 3;
    const int* src = ei;
    const int* dst = ei + E;
    const int nb = (N + SCB - 1) / SCB;

    char* w = (char*)d_ws;
    size_t off = 0;
    auto alloc = [&](size_t bytes) -> void* {
        void* p = w + off;
        off += (bytes + 255) & ~(size_t)255;
        return p;
    };
    float* Pb  = (float*)alloc((size_t)N * HD * 4);  // P fp32
    float* Qb  = (float*)alloc((size_t)N * HD * 4);  // Q fp32
    us* S_h = (us*)alloc((size_t)N * HD * 2);        // S hi; aliased as x_h
    us* S_l = (us*)alloc((size_t)N * HD * 2);        // S lo; aliased as x_l
    us* h_h = (us*)alloc((size_t)N * HD * 2);
    us* h_l = (us*)alloc((size_t)N * HD * 2);
    us* x_h = S_h;                                   // alias: x pair over S pair
    us* x_l = S_l;
    float* fold  = (float*)alloc((size_t)L * HD * HD * 4);
    float* bvec2 = (float*)alloc((size_t)L * HD * 4);
    us* embt_h = (us*)alloc((size_t)128 * 64 * 2);
    us* embt_l = (us*)alloc((size_t)128 * 64 * 2);
    us* WPQt_h = (us*)alloc((size_t)L * 256 * 128 * 2);  // [256 j][128 k]
    us* WPQt_l = (us*)alloc((size_t)L * 256 * 128 * 2);
    us* Wcbt_h = (us*)alloc((size_t)L * 128 * 256 * 2);  // [128 j][256 k]
    us* Wcbt_l = (us*)alloc((size_t)L * 128 * 256 * 2);
    us* U2t_h  = (us*)alloc((size_t)L * 128 * 128 * 2);
    us* U2t_l  = (us*)alloc((size_t)L * 128 * 128 * 2);
    int*   degi   = (int*)alloc((size_t)N * 4);
    float* degf   = (float*)alloc((size_t)N * 4);
    int*   rowptr = (int*)alloc((size_t)(N + 1) * 4);
    int*   cursor = (int*)alloc((size_t)N * 4);
    int*   thrpre = (int*)alloc((size_t)nb * 256 * 4);
    int*   bsum   = (int*)alloc((size_t)(nb + 1) * 4);
    int*   boff   = (int*)alloc((size_t)(nb + 1) * 4);
    int*   gcnt   = (int*)alloc(256 * 4);
    float* gsum   = (float*)alloc((size_t)G * HD * 4);
    float* gmax   = (float*)alloc((size_t)G * HD * 4);
    int*   csr_src = (int*)alloc((size_t)E * 4);
    int*   csr_eid = (int*)alloc((size_t)E * 4);
    float* ea_p = nullptr;
    if (ws_size && off + (size_t)E * 16 * 4 + 256 <= ws_size)
        ea_p = (float*)alloc((size_t)E * 16 * 4);
    (void)n_in; (void)out_size;

    hipMemsetAsync(degi, 0, (size_t)N * 4, stream);
    hipMemsetAsync(gcnt, 0, 256 * 4, stream);
    hipMemsetAsync(gsum, 0, (size_t)G * HD * 4, stream);
    hipMemsetAsync(gmax, 0, (size_t)G * HD * 4, stream);

    // ---- CSR build (parallel scan; scatter fuses ea permutation) ----
    int mEN = (E > N ? E : N);
    k_deghist<<<(mEN + 255) / 256, 256, 0, stream>>>(dst, degi, E, batch, gcnt, N);
    k_scan1<<<nb, 256, 0, stream>>>(degi, thrpre, bsum, N);
    k_scan2<<<1, 64, 0, stream>>>(bsum, boff, nb);
    k_scan3<<<nb, 256, 0, stream>>>(degi, thrpre, boff, rowptr, cursor, degf, N, E);
    k_scatter<<<(E + 255) / 256, 256, 0, stream>>>(dst, src, cursor, ea,
                                                   csr_src, csr_eid, ea_p, E);

    // ---- weight folds + conversions ----
    k_foldW<<<L * 8, 256, 0, stream>>>(msg_W2, upd_W1, fold);
    k_foldb<<<L, 128, 0, stream>>>(msg_b2, upd_W1, bvec2);

    k_cvtA<<<(int)(((long)N * 64 + 255) / 256), 256, 0, stream>>>(x, x_h, x_l, (long)N * 64);
    k_cvtW<<<dim3(32, 1), 256, 0, stream>>>(emb_W, 0, 64, embt_h, embt_l, 0);
    k_cvtW<<<dim3(64, L), 256, 0, stream>>>(msg_W1, 272 * 128, 128,
                                            WPQt_h, WPQt_l, 256 * 128);
    k_cvtW<<<dim3(64, L), 256, 0, stream>>>(msg_W1 + 128 * 128, 272 * 128, 128,
                                            WPQt_h + 128 * 128, WPQt_l + 128 * 128,
                                            256 * 128);
    k_cvtW2<<<dim3(128, L), 256, 0, stream>>>(upd_W1, 256 * 128, fold, 128 * 128,
                                              128, 256, Wcbt_h, Wcbt_l, 128 * 256);
    k_cvtW<<<dim3(64, L), 256, 0, stream>>>(upd_W2, 128 * 128, 128,
                                            U2t_h, U2t_l, 128 * 128);

    const int gb = (N + 63) / 64;
    const int eblk = 2048;
    const int echunk = (N + eblk * 4 - 1) / (eblk * 4);
    // ---- embed: h = x @ emb_W + emb_b (no relu) -> h pair ----
    k_mgemm<2, 64, false, false, false, false, true><<<dim3(gb, 1), 512, 0, stream>>>(
        x_h, x_l, nullptr, nullptr, embt_h, embt_l,
        emb_b, nullptr, nullptr, nullptr, nullptr, h_h, h_l, N);

    for (int l = 0; l < L; ++l) {
        const float* W1 = msg_W1 + (size_t)l * 272 * HD;
        // [P|Q] = h @ [Wa|Wb] (+b1 on P cols) -> Pb, Qb fp32, one dispatch
        k_mgemm<4, 128, false, false, false, true, false><<<dim3(gb, 2), 512, 0, stream>>>(
            h_h, h_l, nullptr, nullptr,
            WPQt_h + (size_t)l * 256 * 128, WPQt_l + (size_t)l * 256 * 128,
            msg_b1 + (size_t)l * HD, nullptr, nullptr, Pb, Qb, nullptr, nullptr, N);
        // S[n] = sum_in relu(P[n] + Q[src] + ea@Wc) -> bf16 pair
        if (ea_p)
            k_edge<true><<<eblk, 256, 0, stream>>>(Pb, Qb, ea_p, rowptr,
                                                   csr_src, nullptr,
                                                   W1 + 256 * HD, S_h, S_l, N, echunk);
        else
            k_edge<false><<<eblk, 256, 0, stream>>>(Pb, Qb, ea, rowptr,
                                                    csr_src, csr_eid,
                                                    W1 + 256 * HD, S_h, S_l, N, echunk);
        // fused update: U = relu([h|S]@Wcb + b1u + deg*bvec2); h = relu(U@U2 + b2u)
        k_upd<<<gb, 512, 0, stream>>>(
            h_h, h_l, S_h, S_l,
            Wcbt_h + (size_t)l * 128 * 256, Wcbt_l + (size_t)l * 128 * 256,
            upd_b1 + (size_t)l * HD, bvec2 + (size_t)l * HD, degf,
            U2t_h + (size_t)l * 128 * 128, U2t_l + (size_t)l * 128 * 128,
            upd_b2 + (size_t)l * HD,
            h_h, h_l, N);
    }

    k_pool2<<<1024, 256, 0, stream>>>(h_h, h_l, batch, gsum, (unsigned int*)gmax, N);
    k_cls<<<G, 128, 0, stream>>>(gsum, gmax, gcnt, cW1, cb1, cW2, cb2, cW3, cb3,
                                 (float*)d_out);
}

// Round 15
// 685.464 us; speedup vs baseline: 1.0576x; 1.0576x over previous
//
#include <hip/hip_runtime.h>
#include <hip/hip_bf16.h>

#define HD 128
#define SCB 2048   // elements per scan block

typedef __attribute__((ext_vector_type(8))) short short8v;
typedef __attribute__((ext_vector_type(4))) float f32x4;
typedef unsigned short us;

__device__ __forceinline__ us f2bf(float f) {
    union { float f; unsigned u; } c; c.f = f;
    unsigned u = c.u;
    return (us)((u + 0x7fffu + ((u >> 16) & 1u)) >> 16);
}
__device__ __forceinline__ float bf2f(us b) {
    union { unsigned u; float f; } c; c.u = ((unsigned)b) << 16;
    return c.f;
}

// async global->LDS, 16B per lane; LDS dest must be wave-uniform base + lane*16
__device__ __forceinline__ void gload16(const void* g, void* l) {
    __builtin_amdgcn_global_load_lds(
        (const __attribute__((address_space(1))) unsigned int*)g,
        (__attribute__((address_space(3))) unsigned int*)l,
        16, 0, 0);
}

// ---------------------------------------------------------------------------
// MFMA node GEMM, fp32 via bf16 hi/lo split (3 MFMA per logical fp32 term).
// Block: 512 threads = 8 waves; tile 64 rows x 128 cols (wave = 64r x 16c).
// A staged via global_load_lds: LINEAR LDS dest + pre-swizzled global source
// (byte (c*16)^((row&7)<<4)); compute reads use the same XOR (involution).
// B (weights, [col][K]) in registers per wave (L2-hot).
// ---------------------------------------------------------------------------
template<int KSTEPS, int K1S, bool HASA2, bool RELU, bool DEGB, bool WF32, bool WBF>
__global__ __launch_bounds__(512) void k_mgemm(
    const us* __restrict__ A1h, const us* __restrict__ A1l,
    const us* __restrict__ A2h, const us* __restrict__ A2l,
    const us* __restrict__ Wth, const us* __restrict__ Wtl,
    const float* __restrict__ bias,
    const float* __restrict__ bdeg, const float* __restrict__ deg,
    float* __restrict__ Cf0, float* __restrict__ Cf1,
    us* __restrict__ Ch, us* __restrict__ Cl,
    int nrows)
{
    constexpr int K   = KSTEPS * 32;
    constexpr int CPR = K / 8;              // 16B chunks per row
    constexpr int ITER = (64 * CPR) / 512;  // staging chunks per thread
    __shared__ us As_h[64 * K];
    __shared__ us As_l[64 * K];

    const int tid  = threadIdx.x;
    const int wv   = tid >> 6;
    const int lane = tid & 63;
    const int r    = lane & 15;
    const int g    = lane >> 4;
    const int rb   = blockIdx.x * 64;
    const int col  = blockIdx.y * 128 + wv * 16 + r;

    short8v bh[KSTEPS], bl[KSTEPS];
    {
        size_t wbase = (size_t)col * K + (size_t)(g * 8);
#pragma unroll
        for (int s = 0; s < KSTEPS; ++s) {
            bh[s] = *(const short8v*)(Wth + wbase + s * 32);
            bl[s] = *(const short8v*)(Wtl + wbase + s * 32);
        }
    }

    // ---- stage A: linear LDS dest, swizzled global source ----
#pragma unroll
    for (int i = 0; i < ITER; ++i) {
        int f = tid + i * 512;
        int row = f / CPR, c = f % CPR;
        int grow = rb + row; if (grow >= nrows) grow = nrows - 1;
        int sb = (c * 16) ^ ((row & 7) << 4);   // source byte within row
        const char *gh, *gl;
        if (!HASA2 || sb < K1S * 2) {
            gh = (const char*)A1h + (size_t)grow * (K1S * 2) + sb;
            gl = (const char*)A1l + (size_t)grow * (K1S * 2) + sb;
        } else {
            gh = (const char*)A2h + (size_t)grow * ((K - K1S) * 2) + (sb - K1S * 2);
            gl = (const char*)A2l + (size_t)grow * ((K - K1S) * 2) + (sb - K1S * 2);
        }
        gload16(gh, (char*)As_h + (size_t)f * 16);
        gload16(gl, (char*)As_l + (size_t)f * 16);
    }
    __syncthreads();

    f32x4 acc[4];
#pragma unroll
    for (int t = 0; t < 4; ++t) acc[t] = (f32x4){0.f, 0.f, 0.f, 0.f};

#pragma unroll
    for (int s = 0; s < KSTEPS; ++s) {
#pragma unroll
        for (int t = 0; t < 4; ++t) {
            int row = t * 16 + r;
            int boff = row * (K * 2) + (((s * 64) + g * 16) ^ ((row & 7) << 4));
            short8v ah = *(const short8v*)((const char*)As_h + boff);
            short8v al = *(const short8v*)((const char*)As_l + boff);
            acc[t] = __builtin_amdgcn_mfma_f32_16x16x32_bf16(ah, bh[s], acc[t], 0, 0, 0);
            acc[t] = __builtin_amdgcn_mfma_f32_16x16x32_bf16(al, bh[s], acc[t], 0, 0, 0);
            acc[t] = __builtin_amdgcn_mfma_f32_16x16x32_bf16(ah, bl[s], acc[t], 0, 0, 0);
        }
    }

    const float bb = (bias && col < 128) ? bias[col] : 0.f;
    const float bd = (DEGB && col < 128) ? bdeg[col] : 0.f;
    const int jc = col & 127;
#pragma unroll
    for (int t = 0; t < 4; ++t) {
#pragma unroll
        for (int i = 0; i < 4; ++i) {
            int row = rb + t * 16 + g * 4 + i;
            if (row >= nrows) continue;
            float v = acc[t][i] + bb;
            if (DEGB) v += deg[row] * bd;
            if (RELU) v = fmaxf(v, 0.f);
            size_t o = (size_t)row * HD + jc;
            if (WF32) (col < 128 ? Cf0 : Cf1)[o] = v;
            if (WBF) {
                us hh = f2bf(v);
                Ch[o] = hh;
                Cl[o] = f2bf(v - bf2f(hh));
            }
        }
    }
}

// ---------------------------------------------------------------------------
// Fused update: U = relu([h|S]@Wcb + b1 + deg*bdeg) ; hout = relu(U@U2 + b2).
// Stage-1 A staged via global_load_lds (swizzled source); U-tile written back
// into the A LDS (barrier-guarded) for stage 2.
// ---------------------------------------------------------------------------
__global__ __launch_bounds__(512) void k_upd(
    const us* __restrict__ A1h, const us* __restrict__ A1l,
    const us* __restrict__ A2h, const us* __restrict__ A2l,
    const us* __restrict__ Wth, const us* __restrict__ Wtl,   // [128 j][256 k]
    const float* __restrict__ b1,
    const float* __restrict__ bdeg, const float* __restrict__ deg,
    const us* __restrict__ W2th, const us* __restrict__ W2tl, // [128 j][128 k]
    const float* __restrict__ b2,
    us* __restrict__ out_h, us* __restrict__ out_l,
    int nrows)
{
    constexpr int K = 256;
    constexpr int CPR = K / 8;
    constexpr int ITER = (64 * CPR) / 512;
    __shared__ us As_h[64 * K];
    __shared__ us As_l[64 * K];

    const int tid  = threadIdx.x;
    const int wv   = tid >> 6;
    const int lane = tid & 63;
    const int r    = lane & 15;
    const int g    = lane >> 4;
    const int rb   = blockIdx.x * 64;
    const int col  = wv * 16 + r;

    short8v bh[8], bl[8];
    {
        size_t wbase = (size_t)col * K + (size_t)(g * 8);
#pragma unroll
        for (int s = 0; s < 8; ++s) {
            bh[s] = *(const short8v*)(Wth + wbase + s * 32);
            bl[s] = *(const short8v*)(Wtl + wbase + s * 32);
        }
    }

    // stage A = [h|S] (each row: 256B of h, 256B of S), swizzled source
#pragma unroll
    for (int i = 0; i < ITER; ++i) {
        int f = tid + i * 512;
        int row = f / CPR, c = f % CPR;
        int grow = rb + row; if (grow >= nrows) grow = nrows - 1;
        int sb = (c * 16) ^ ((row & 7) << 4);
        const char *gh, *gl;
        if (sb < 256) {
            gh = (const char*)A1h + (size_t)grow * 256 + sb;
            gl = (const char*)A1l + (size_t)grow * 256 + sb;
        } else {
            gh = (const char*)A2h + (size_t)grow * 256 + (sb - 256);
            gl = (const char*)A2l + (size_t)grow * 256 + (sb - 256);
        }
        gload16(gh, (char*)As_h + (size_t)f * 16);
        gload16(gl, (char*)As_l + (size_t)f * 16);
    }
    __syncthreads();

    f32x4 acc[4];
#pragma unroll
    for (int t = 0; t < 4; ++t) acc[t] = (f32x4){0.f, 0.f, 0.f, 0.f};
#pragma unroll
    for (int s = 0; s < 8; ++s) {
#pragma unroll
        for (int t = 0; t < 4; ++t) {
            int row = t * 16 + r;
            int boff = row * (K * 2) + (((s * 64) + g * 16) ^ ((row & 7) << 4));
            short8v ah = *(const short8v*)((const char*)As_h + boff);
            short8v al = *(const short8v*)((const char*)As_l + boff);
            acc[t] = __builtin_amdgcn_mfma_f32_16x16x32_bf16(ah, bh[s], acc[t], 0, 0, 0);
            acc[t] = __builtin_amdgcn_mfma_f32_16x16x32_bf16(al, bh[s], acc[t], 0, 0, 0);
            acc[t] = __builtin_amdgcn_mfma_f32_16x16x32_bf16(ah, bl[s], acc[t], 0, 0, 0);
        }
    }
    __syncthreads();   // all As reads complete; safe to overwrite with U tile

    short8v b2h[4], b2l[4];
    {
        size_t wbase = (size_t)col * 128 + (size_t)(g * 8);
#pragma unroll
        for (int s = 0; s < 4; ++s) {
            b2h[s] = *(const short8v*)(W2th + wbase + s * 32);
            b2l[s] = *(const short8v*)(W2tl + wbase + s * 32);
        }
    }

    {
        const float bb = b1[col];
        const float bd = bdeg[col];
#pragma unroll
        for (int t = 0; t < 4; ++t) {
#pragma unroll
            for (int i = 0; i < 4; ++i) {
                int lrow = t * 16 + g * 4 + i;
                int grow = rb + lrow;
                float dg = (grow < nrows) ? deg[grow] : 0.f;
                float v = acc[t][i] + bb + dg * bd;
                v = fmaxf(v, 0.f);
                us uh = f2bf(v);
                us ul = f2bf(v - bf2f(uh));
                int byte = lrow * 256 + ((col * 2) ^ ((lrow & 7) << 4));
                *(us*)((char*)As_h + byte) = uh;
                *(us*)((char*)As_l + byte) = ul;
            }
        }
    }
    __syncthreads();

    f32x4 acc2[4];
#pragma unroll
    for (int t = 0; t < 4; ++t) acc2[t] = (f32x4){0.f, 0.f, 0.f, 0.f};
#pragma unroll
    for (int s = 0; s < 4; ++s) {
#pragma unroll
        for (int t = 0; t < 4; ++t) {
            int row = t * 16 + r;
            int boff = row * 256 + (((s * 64) + g * 16) ^ ((row & 7) << 4));
            short8v ah = *(const short8v*)((const char*)As_h + boff);
            short8v al = *(const short8v*)((const char*)As_l + boff);
            acc2[t] = __builtin_amdgcn_mfma_f32_16x16x32_bf16(ah, b2h[s], acc2[t], 0, 0, 0);
            acc2[t] = __builtin_amdgcn_mfma_f32_16x16x32_bf16(al, b2h[s], acc2[t], 0, 0, 0);
            acc2[t] = __builtin_amdgcn_mfma_f32_16x16x32_bf16(ah, b2l[s], acc2[t], 0, 0, 0);
        }
    }
    const float bb2 = b2[col];
#pragma unroll
    for (int t = 0; t < 4; ++t) {
#pragma unroll
        for (int i = 0; i < 4; ++i) {
            int row = rb + t * 16 + g * 4 + i;
            if (row >= nrows) continue;
            float v = fmaxf(acc2[t][i] + bb2, 0.f);
            size_t o = (size_t)row * HD + col;
            us hh = f2bf(v);
            out_h[o] = hh;
            out_l[o] = f2bf(v - bf2f(hh));
        }
    }
}

// ---------------------------------------------------------------------------
// Conversions
// ---------------------------------------------------------------------------
__global__ void k_cvtA(const float* __restrict__ src,
                       us* __restrict__ dh, us* __restrict__ dl, long n)
{
    long i = (long)blockIdx.x * blockDim.x + threadIdx.x;
    if (i >= n) return;
    float v = src[i];
    us h = f2bf(v);
    dh[i] = h;
    dl[i] = f2bf(v - bf2f(h));
}

__global__ void k_cvtW(const float* __restrict__ src, long sstride, int K,
                       us* __restrict__ dh, us* __restrict__ dl, long dstride)
{
    int l = blockIdx.y;
    int idx = blockIdx.x * 256 + threadIdx.x;
    if (idx >= K * 128) return;
    int k = idx >> 7, j = idx & 127;
    float v = src[(size_t)l * sstride + (size_t)k * 128 + j];
    us h = f2bf(v);
    size_t o = (size_t)l * dstride + (size_t)j * K + k;
    dh[o] = h;
    dl[o] = f2bf(v - bf2f(h));
}

__global__ void k_cvtW2(const float* __restrict__ srcA, long strideA,
                        const float* __restrict__ srcB, long strideB,
                        int K1s, int K,
                        us* __restrict__ dh, us* __restrict__ dl, long dstride)
{
    int l = blockIdx.y;
    int idx = blockIdx.x * 256 + threadIdx.x;
    if (idx >= K * 128) return;
    int k = idx >> 7, j = idx & 127;
    float v = (k < K1s)
        ? srcA[(size_t)l * strideA + (size_t)k * 128 + j]
        : srcB[(size_t)l * strideB + (size_t)(k - K1s) * 128 + j];
    us h = f2bf(v);
    size_t o = (size_t)l * dstride + (size_t)j * K + k;
    dh[o] = h;
    dl[o] = f2bf(v - bf2f(h));
}

// ---------------------------------------------------------------------------
// CSR build: deg+hist -> 3-phase parallel scan -> scatter (fused ea permute)
// ---------------------------------------------------------------------------
__global__ void k_deghist(const int* __restrict__ dst, int* __restrict__ degi, int E,
                          const int* __restrict__ batch, int* __restrict__ gcnt, int N)
{
    int i = blockIdx.x * blockDim.x + threadIdx.x;
    if (i < E) atomicAdd(&degi[dst[i]], 1);
    if (i < N) atomicAdd(&gcnt[batch[i]], 1);
}

__global__ __launch_bounds__(256) void k_scan1(const int* __restrict__ degi,
                                               int* __restrict__ thrpre,
                                               int* __restrict__ bsum, int N)
{
    __shared__ int sc[256];
    const int t = threadIdx.x, b = blockIdx.x;
    int i0 = b * SCB + t * 8;
    int s = 0;
#pragma unroll
    for (int q = 0; q < 8; ++q) {
        int i = i0 + q;
        if (i < N) s += degi[i];
    }
    sc[t] = s;
    __syncthreads();
    for (int o = 1; o < 256; o <<= 1) {
        int v = (t >= o) ? sc[t - o] : 0;
        __syncthreads();
        sc[t] += v;
        __syncthreads();
    }
    thrpre[b * 256 + t] = sc[t] - s;
    if (t == 255) bsum[b] = sc[255];
}

__global__ void k_scan2(const int* __restrict__ bsum, int* __restrict__ boff, int nb)
{
    if (threadIdx.x == 0 && blockIdx.x == 0) {
        int run = 0;
        for (int b = 0; b < nb; ++b) { boff[b] = run; run += bsum[b]; }
    }
}

__global__ __launch_bounds__(256) void k_scan3(
    const int* __restrict__ degi, const int* __restrict__ thrpre,
    const int* __restrict__ boff,
    int* __restrict__ rowptr, int* __restrict__ cursor,
    float* __restrict__ degf, int N, int E)
{
    const int t = threadIdx.x, b = blockIdx.x;
    int run = boff[b] + thrpre[b * 256 + t];
    int i0 = b * SCB + t * 8;
#pragma unroll
    for (int q = 0; q < 8; ++q) {
        int i = i0 + q;
        if (i < N) {
            int d = degi[i];
            rowptr[i] = run;
            cursor[i] = run;
            degf[i] = (float)d;
            run += d;
        }
    }
    if (b == 0 && t == 0) rowptr[N] = E;
}

__global__ void k_scatter(const int* __restrict__ dst, const int* __restrict__ src,
                          int* __restrict__ cursor,
                          const float* __restrict__ ea,
                          int* __restrict__ csr_src, int* __restrict__ csr_eid,
                          float* __restrict__ ea_p, int E)
{
    int e = blockIdx.x * blockDim.x + threadIdx.x;
    if (e >= E) return;
    int d = dst[e];
    int pos = atomicAdd(&cursor[d], 1);
    csr_src[pos] = src[e];
    if (ea_p) {
        const float4* s4 = (const float4*)&ea[(size_t)e * 16];
        float4* d4 = (float4*)&ea_p[(size_t)pos * 16];
        d4[0] = s4[0]; d4[1] = s4[1]; d4[2] = s4[2]; d4[3] = s4[3];
    } else {
        csr_eid[pos] = e;
    }
}

// ---------------------------------------------------------------------------
// Weight folds: fold = W2 @ U1b ; bvec2 = b2 @ U1b
// ---------------------------------------------------------------------------
__global__ __launch_bounds__(256) void k_foldW(
    const float* __restrict__ msg_W2, const float* __restrict__ upd_W1,
    float* __restrict__ fold)
{
    int l = blockIdx.x >> 3, rb = blockIdx.x & 7;
    const float* W2  = msg_W2 + (size_t)l * HD * HD;
    const float* U1b = upd_W1 + (size_t)l * 256 * HD + (size_t)HD * HD;
    float* Wout = fold + (size_t)l * HD * HD;
    int j = threadIdx.x & 127;
    int rh = threadIdx.x >> 7;
    int r0 = rb * 16 + rh * 8;
    float acc[8] = {0.f,0.f,0.f,0.f,0.f,0.f,0.f,0.f};
    for (int k = 0; k < HD; ++k) {
        float u = U1b[(size_t)k * HD + j];
#pragma unroll
        for (int rr = 0; rr < 8; ++rr)
            acc[rr] = fmaf(W2[(size_t)(r0 + rr) * HD + k], u, acc[rr]);
    }
#pragma unroll
    for (int rr = 0; rr < 8; ++rr)
        Wout[(size_t)(r0 + rr) * HD + j] = acc[rr];
}

__global__ __launch_bounds__(128) void k_foldb(
    const float* __restrict__ msg_b2, const float* __restrict__ upd_W1,
    float* __restrict__ bvec2)
{
    int l = blockIdx.x, j = threadIdx.x;
    const float* U1b = upd_W1 + (size_t)l * 256 * HD + (size_t)HD * HD;
    const float* b2 = msg_b2 + (size_t)l * HD;
    float acc = 0.f;
    for (int k = 0; k < HD; ++k) acc = fmaf(b2[k], U1b[(size_t)k * HD + j], acc);
    bvec2[(size_t)l * HD + j] = acc;
}

// ---------------------------------------------------------------------------
// Edge gather: S[n] = sum_{e:dst=n} relu(P[n] + Q[src] + ea@Wc)
// Wave per node, 2 dims/lane, 16-edge CLAMPED batch (ceil(deg/16) dependent
// round trips; 32 Q-gathers in flight). Edge indices via one coalesced
// lane-load + readlane broadcast. (Round-10 proven config: 93 us.)
// ---------------------------------------------------------------------------
#define EB 16
template<bool PERM>
__global__ __launch_bounds__(256) void k_edge(
    const float* __restrict__ P, const float* __restrict__ Q,
    const float* __restrict__ EA,
    const int* __restrict__ rowptr,
    const int* __restrict__ csr_src, const int* __restrict__ csr_eid,
    const float* __restrict__ W1c,
    us* __restrict__ Sh, us* __restrict__ Sl, int N)
{
    const int lane = threadIdx.x & 63;
    const int node = __builtin_amdgcn_readfirstlane(blockIdx.x * 4 + (threadIdx.x >> 6));
    if (node >= N) return;
    float wA[16], wB[16];
#pragma unroll
    for (int k = 0; k < 16; ++k) {
        wA[k] = W1c[k * HD + lane];
        wB[k] = W1c[k * HD + 64 + lane];
    }
    const int beg = __builtin_amdgcn_readfirstlane(rowptr[node]);
    const int end = __builtin_amdgcn_readfirstlane(rowptr[node + 1]);
    const float pA = P[(size_t)node * HD + lane];
    const float pB = P[(size_t)node * HD + 64 + lane];
    float accA = 0.f, accB = 0.f;

    for (int i = beg; i < end; i += EB) {
        // lane r (r<16) loads csr_src[min(i+r,end-1)]; broadcast via readlane
        int myi = i + (lane & 15);
        myi = (myi < end) ? myi : (end - 1);
        int myidx = PERM ? myi : csr_eid[myi];
        int mysrc = csr_src[myi];
        int sv[EB], ei[EB];
#pragma unroll
        for (int r = 0; r < EB; ++r) {
            sv[r] = __builtin_amdgcn_readlane(mysrc, r);
            ei[r] = PERM ? 0 : __builtin_amdgcn_readlane(myidx, r);
        }
        float qA[EB], qB[EB];
#pragma unroll
        for (int r = 0; r < EB; ++r) {
            qA[r] = Q[(size_t)sv[r] * HD + lane];
            qB[r] = Q[(size_t)sv[r] * HD + 64 + lane];
        }
#pragma unroll
        for (int r = 0; r < EB; ++r) {
            int ii = i + r; ii = (ii < end) ? ii : (end - 1);
            const float4* Ev = PERM ? (const float4*)&EA[(size_t)ii * 16]
                                    : (const float4*)&EA[(size_t)ei[r] * 16];
            float4 v0 = Ev[0], v1 = Ev[1], v2 = Ev[2], v3 = Ev[3];
            float tA = pA + qA[r], tB = pB + qB[r];
            tA = fmaf(v0.x, wA[0],  tA); tB = fmaf(v0.x, wB[0],  tB);
            tA = fmaf(v0.y, wA[1],  tA); tB = fmaf(v0.y, wB[1],  tB);
            tA = fmaf(v0.z, wA[2],  tA); tB = fmaf(v0.z, wB[2],  tB);
            tA = fmaf(v0.w, wA[3],  tA); tB = fmaf(v0.w, wB[3],  tB);
            tA = fmaf(v1.x, wA[4],  tA); tB = fmaf(v1.x, wB[4],  tB);
            tA = fmaf(v1.y, wA[5],  tA); tB = fmaf(v1.y, wB[5],  tB);
            tA = fmaf(v1.z, wA[6],  tA); tB = fmaf(v1.z, wB[6],  tB);
            tA = fmaf(v1.w, wA[7],  tA); tB = fmaf(v1.w, wB[7],  tB);
            tA = fmaf(v2.x, wA[8],  tA); tB = fmaf(v2.x, wB[8],  tB);
            tA = fmaf(v2.y, wA[9],  tA); tB = fmaf(v2.y, wB[9],  tB);
            tA = fmaf(v2.z, wA[10], tA); tB = fmaf(v2.z, wB[10], tB);
            tA = fmaf(v2.w, wA[11], tA); tB = fmaf(v2.w, wB[11], tB);
            tA = fmaf(v3.x, wA[12], tA); tB = fmaf(v3.x, wB[12], tB);
            tA = fmaf(v3.y, wA[13], tA); tB = fmaf(v3.y, wB[13], tB);
            tA = fmaf(v3.z, wA[14], tA); tB = fmaf(v3.z, wB[14], tB);
            tA = fmaf(v3.w, wA[15], tA); tB = fmaf(v3.w, wB[15], tB);
            bool ok = (i + r) < end;
            accA += ok ? fmaxf(tA, 0.f) : 0.f;
            accB += ok ? fmaxf(tB, 0.f) : 0.f;
        }
    }
    size_t oA = (size_t)node * HD + lane;
    size_t oB = oA + 64;
    us hA = f2bf(accA);
    us hB = f2bf(accB);
    Sh[oA] = hA; Sl[oA] = f2bf(accA - bf2f(hA));
    Sh[oB] = hB; Sl[oB] = f2bf(accB - bf2f(hB));
}

// ---------------------------------------------------------------------------
// Pool (segment mean/max over sorted batch) from bf16 hi/lo h; then classifier.
// ---------------------------------------------------------------------------
__global__ __launch_bounds__(256) void k_pool2(
    const us* __restrict__ hh, const us* __restrict__ hl,
    const int* __restrict__ batch,
    float* __restrict__ gsum, unsigned int* __restrict__ gmax, int N)
{
    int nchunk = (N + gridDim.x - 1) / gridDim.x;
    int n0 = blockIdx.x * nchunk;
    int n1 = n0 + nchunk; if (n1 > N) n1 = N;
    int j = threadIdx.x & 127;
    int half = threadIdx.x >> 7;
    float s = 0.f, m = 0.f; int gcur = -1;
    for (int n = n0 + half; n < n1; n += 2) {
        int g = batch[n];
        if (g != gcur) {
            if (gcur >= 0) {
                atomicAdd(&gsum[(size_t)gcur * HD + j], s);
                atomicMax(&gmax[(size_t)gcur * HD + j], __float_as_uint(m));
            }
            gcur = g; s = 0.f; m = 0.f;
        }
        size_t o = (size_t)n * HD + j;
        float v = bf2f(hh[o]) + bf2f(hl[o]);
        s += v; m = fmaxf(m, v);
    }
    if (gcur >= 0) {
        atomicAdd(&gsum[(size_t)gcur * HD + j], s);
        atomicMax(&gmax[(size_t)gcur * HD + j], __float_as_uint(m));
    }
}

__global__ __launch_bounds__(128) void k_cls(
    const float* __restrict__ gsum, const float* __restrict__ gmax,
    const int* __restrict__ gcnt,
    const float* __restrict__ W1, const float* __restrict__ b1,
    const float* __restrict__ W2, const float* __restrict__ b2,
    const float* __restrict__ W3, const float* __restrict__ b3,
    float* __restrict__ out)
{
    __shared__ float rep[256];
    __shared__ float z1[128];
    __shared__ float z2[64];
    const int g = blockIdx.x;
    const int j = threadIdx.x;
    float cntf = (float)gcnt[g];
    rep[j]       = gsum[(size_t)g * HD + j] / fmaxf(cntf, 1.f);
    rep[128 + j] = gmax[(size_t)g * HD + j];
    __syncthreads();
    float a = 0.f;
    for (int k = 0; k < 256; ++k) a = fmaf(rep[k], W1[(size_t)k * 128 + j], a);
    z1[j] = fmaxf(a + b1[j], 0.f);
    __syncthreads();
    if (j < 64) {
        float b = 0.f;
        for (int k = 0; k < 128; ++k) b = fmaf(z1[k], W2[(size_t)k * 64 + j], b);
        z2[j] = fmaxf(b + b2[j], 0.f);
    }
    __syncthreads();
    if (j < 2) {
        float c = 0.f;
        for (int k = 0; k < 64; ++k) c = fmaf(z2[k], W3[(size_t)k * 2 + j], c);
        out[(size_t)g * 2 + j] = c + b3[j];
    }
}

extern "C" void kernel_launch(void* const* d_in, const int* in_sizes, int n_in,
                              void* d_out, int out_size, void* d_ws, size_t ws_size,
                              hipStream_t stream) {
    const float* x      = (const float*)d_in[0];
    const float* ea     = (const float*)d_in[1];
    const int*   ei     = (const int*)d_in[2];
    const int*   batch  = (const int*)d_in[3];
    const float* emb_W  = (const float*)d_in[4];
    const float* emb_b  = (const float*)d_in[5];
    const float* msg_W1 = (const float*)d_in[6];
    const float* msg_b1 = (const float*)d_in[7];
    const float* msg_W2 = (const float*)d_in[8];
    const float* msg_b2 = (const float*)d_in[9];
    const float* upd_W1 = (const float*)d_in[10];
    const float* upd_b1 = (const float*)d_in[11];
    const float* upd_W2 = (const float*)d_in[12];
    const float* upd_b2 = (const float*)d_in[13];
    const float* cW1 = (const float*)d_in[14];
    const float* cb1 = (const float*)d_in[15];
    const float* cW2 = (const float*)d_in[16];
    const float* cb2 = (const float*)d_in[17];
    const float* cW3 = (const float*)d_in[18];
    const float* cb3 = (const float*)d_in[19];

    const int N = in_sizes[0] / 64;
    const int E = in_sizes[1] / 16;
    const int G = 256, L = 3;
    const int* src = ei;
    const int* dst = ei + E;
    const int nb = (N + SCB - 1) / SCB;

    char* w = (char*)d_ws;
    size_t off = 0;
    auto alloc = [&](size_t bytes) -> void* {
        void* p = w + off;
        off += (bytes + 255) & ~(size_t)255;
        return p;
    };
    float* Pb  = (float*)alloc((size_t)N * HD * 4);  // P fp32
    float* Qb  = (float*)alloc((size_t)N * HD * 4);  // Q fp32
    us* S_h = (us*)alloc((size_t)N * HD * 2);        // S hi; aliased as x_h
    us* S_l = (us*)alloc((size_t)N * HD * 2);        // S lo; aliased as x_l
    us* h_h = (us*)alloc((size_t)N * HD * 2);
    us* h_l = (us*)alloc((size_t)N * HD * 2);
    us* x_h = S_h;                                   // alias: x pair over S pair
    us* x_l = S_l;
    float* fold  = (float*)alloc((size_t)L * HD * HD * 4);
    float* bvec2 = (float*)alloc((size_t)L * HD * 4);
    us* embt_h = (us*)alloc((size_t)128 * 64 * 2);
    us* embt_l = (us*)alloc((size_t)128 * 64 * 2);
    us* WPQt_h = (us*)alloc((size_t)L * 256 * 128 * 2);  // [256 j][128 k]
    us* WPQt_l = (us*)alloc((size_t)L * 256 * 128 * 2);
    us* Wcbt_h = (us*)alloc((size_t)L * 128 * 256 * 2);  // [128 j][256 k]
    us* Wcbt_l = (us*)alloc((size_t)L * 128 * 256 * 2);
    us* U2t_h  = (us*)alloc((size_t)L * 128 * 128 * 2);
    us* U2t_l  = (us*)alloc((size_t)L * 128 * 128 * 2);
    int*   degi   = (int*)alloc((size_t)N * 4);
    float* degf   = (float*)alloc((size_t)N * 4);
    int*   rowptr = (int*)alloc((size_t)(N + 1) * 4);
    int*   cursor = (int*)alloc((size_t)N * 4);
    int*   thrpre = (int*)alloc((size_t)nb * 256 * 4);
    int*   bsum   = (int*)alloc((size_t)(nb + 1) * 4);
    int*   boff   = (int*)alloc((size_t)(nb + 1) * 4);
    int*   gcnt   = (int*)alloc(256 * 4);
    float* gsum   = (float*)alloc((size_t)G * HD * 4);
    float* gmax   = (float*)alloc((size_t)G * HD * 4);
    int*   csr_src = (int*)alloc((size_t)E * 4);
    int*   csr_eid = (int*)alloc((size_t)E * 4);
    float* ea_p = nullptr;
    if (ws_size && off + (size_t)E * 16 * 4 + 256 <= ws_size)
        ea_p = (float*)alloc((size_t)E * 16 * 4);
    (void)n_in; (void)out_size;

    hipMemsetAsync(degi, 0, (size_t)N * 4, stream);
    hipMemsetAsync(gcnt, 0, 256 * 4, stream);
    hipMemsetAsync(gsum, 0, (size_t)G * HD * 4, stream);
    hipMemsetAsync(gmax, 0, (size_t)G * HD * 4, stream);

    // ---- CSR build (parallel scan; scatter fuses ea permutation) ----
    int mEN = (E > N ? E : N);
    k_deghist<<<(mEN + 255) / 256, 256, 0, stream>>>(dst, degi, E, batch, gcnt, N);
    k_scan1<<<nb, 256, 0, stream>>>(degi, thrpre, bsum, N);
    k_scan2<<<1, 64, 0, stream>>>(bsum, boff, nb);
    k_scan3<<<nb, 256, 0, stream>>>(degi, thrpre, boff, rowptr, cursor, degf, N, E);
    k_scatter<<<(E + 255) / 256, 256, 0, stream>>>(dst, src, cursor, ea,
                                                   csr_src, csr_eid, ea_p, E);

    // ---- weight folds + conversions ----
    k_foldW<<<L * 8, 256, 0, stream>>>(msg_W2, upd_W1, fold);
    k_foldb<<<L, 128, 0, stream>>>(msg_b2, upd_W1, bvec2);

    k_cvtA<<<(int)(((long)N * 64 + 255) / 256), 256, 0, stream>>>(x, x_h, x_l, (long)N * 64);
    k_cvtW<<<dim3(32, 1), 256, 0, stream>>>(emb_W, 0, 64, embt_h, embt_l, 0);
    k_cvtW<<<dim3(64, L), 256, 0, stream>>>(msg_W1, 272 * 128, 128,
                                            WPQt_h, WPQt_l, 256 * 128);
    k_cvtW<<<dim3(64, L), 256, 0, stream>>>(msg_W1 + 128 * 128, 272 * 128, 128,
                                            WPQt_h + 128 * 128, WPQt_l + 128 * 128,
                                            256 * 128);
    k_cvtW2<<<dim3(128, L), 256, 0, stream>>>(upd_W1, 256 * 128, fold, 128 * 128,
                                              128, 256, Wcbt_h, Wcbt_l, 128 * 256);
    k_cvtW<<<dim3(64, L), 256, 0, stream>>>(upd_W2, 128 * 128, 128,
                                            U2t_h, U2t_l, 128 * 128);

    const int gb = (N + 63) / 64;
    // ---- embed: h = x @ emb_W + emb_b (no relu) -> h pair ----
    k_mgemm<2, 64, false, false, false, false, true><<<dim3(gb, 1), 512, 0, stream>>>(
        x_h, x_l, nullptr, nullptr, embt_h, embt_l,
        emb_b, nullptr, nullptr, nullptr, nullptr, h_h, h_l, N);

    for (int l = 0; l < L; ++l) {
        const float* W1 = msg_W1 + (size_t)l * 272 * HD;
        // [P|Q] = h @ [Wa|Wb] (+b1 on P cols) -> Pb, Qb fp32, one dispatch
        k_mgemm<4, 128, false, false, false, true, false><<<dim3(gb, 2), 512, 0, stream>>>(
            h_h, h_l, nullptr, nullptr,
            WPQt_h + (size_t)l * 256 * 128, WPQt_l + (size_t)l * 256 * 128,
            msg_b1 + (size_t)l * HD, nullptr, nullptr, Pb, Qb, nullptr, nullptr, N);
        // S[n] = sum_in relu(P[n] + Q[src] + ea@Wc) -> bf16 pair
        if (ea_p)
            k_edge<true><<<(N + 3) / 4, 256, 0, stream>>>(Pb, Qb, ea_p, rowptr,
                                                          csr_src, nullptr,
                                                          W1 + 256 * HD, S_h, S_l, N);
        else
            k_edge<false><<<(N + 3) / 4, 256, 0, stream>>>(Pb, Qb, ea, rowptr,
                                                           csr_src, csr_eid,
                                                           W1 + 256 * HD, S_h, S_l, N);
        // fused update: U = relu([h|S]@Wcb + b1u + deg*bvec2); h = relu(U@U2 + b2u)
        k_upd<<<gb, 512, 0, stream>>>(
            h_h, h_l, S_h, S_l,
            Wcbt_h + (size_t)l * 128 * 256, Wcbt_l + (size_t)l * 128 * 256,
            upd_b1 + (size_t)l * HD, bvec2 + (size_t)l * HD, degf,
            U2t_h + (size_t)l * 128 * 128, U2t_l + (size_t)l * 128 * 128,
            upd_b2 + (size_t)l * HD,
            h_h, h_l, N);
    }

    k_pool2<<<1024, 256, 0, stream>>>(h_h, h_l, batch, gsum, (unsigned int*)gmax, N);
    k_cls<<<G, 128, 0, stream>>>(gsum, gmax, gcnt, cW1, cb1, cW2, cb2, cW3, cb3,
                                 (float*)d_out);
}

// Round 16
// 666.715 us; speedup vs baseline: 1.0874x; 1.0281x over previous
//
#include <hip/hip_runtime.h>
#include <hip/hip_bf16.h>

#define HD 128
#define SCB 2048   // elements per scan block

typedef __attribute__((ext_vector_type(8))) short short8v;
typedef __attribute__((ext_vector_type(4))) float f32x4;
typedef unsigned short us;

__device__ __forceinline__ us f2bf(float f) {
    union { float f; unsigned u; } c; c.f = f;
    unsigned u = c.u;
    return (us)((u + 0x7fffu + ((u >> 16) & 1u)) >> 16);
}
__device__ __forceinline__ float bf2f(us b) {
    union { unsigned u; float f; } c; c.u = ((unsigned)b) << 16;
    return c.f;
}

// async global->LDS, 16B per lane; LDS dest must be wave-uniform base + lane*16
__device__ __forceinline__ void gload16(const void* g, void* l) {
    __builtin_amdgcn_global_load_lds(
        (const __attribute__((address_space(1))) unsigned int*)g,
        (__attribute__((address_space(3))) unsigned int*)l,
        16, 0, 0);
}

// ---------------------------------------------------------------------------
// Fused embed+PQ: h = x@embW + emb_b (K=64); [P|Q] = h@[Wa|Wb] (+b1 on P).
// Block 512 thr = 8 waves, 64-row tile. h tile chained through LDS.
// ---------------------------------------------------------------------------
__global__ __launch_bounds__(512) void k_embpq(
    const us* __restrict__ xh, const us* __restrict__ xl,
    const us* __restrict__ embth, const us* __restrict__ embtl, // [128 j][64 k]
    const float* __restrict__ emb_b,
    const us* __restrict__ wpqh, const us* __restrict__ wpql,   // [256 j][128 k]
    const float* __restrict__ b1msg,
    us* __restrict__ out_h, us* __restrict__ out_l,
    float* __restrict__ Pb, float* __restrict__ Qb, int nrows)
{
    __shared__ us As_h[8192];   // 16KB: x tile (row*128B), then h tile (row*256B)
    __shared__ us As_l[8192];

    const int tid  = threadIdx.x;
    const int wv   = tid >> 6;
    const int lane = tid & 63;
    const int r    = lane & 15;
    const int g    = lane >> 4;
    const int rb   = blockIdx.x * 64;
    const int col  = wv * 16 + r;

    // stage-1 B regs (embW, K=64)
    short8v bh[2], bl[2];
    {
        size_t wbase = (size_t)col * 64 + (size_t)(g * 8);
#pragma unroll
        for (int s = 0; s < 2; ++s) {
            bh[s] = *(const short8v*)(embth + wbase + s * 32);
            bl[s] = *(const short8v*)(embtl + wbase + s * 32);
        }
    }

    // stage x pair: 64 rows x 8 chunks = 512 (1 per thread), swizzled source
    {
        int f = tid;
        int row = f >> 3, c = f & 7;
        int grow = rb + row; if (grow >= nrows) grow = nrows - 1;
        int sb = (c * 16) ^ ((row & 7) << 4);
        gload16((const char*)xh + (size_t)grow * 128 + sb, (char*)As_h + (size_t)f * 16);
        gload16((const char*)xl + (size_t)grow * 128 + sb, (char*)As_l + (size_t)f * 16);
    }
    __syncthreads();

    f32x4 acc[4];
#pragma unroll
    for (int t = 0; t < 4; ++t) acc[t] = (f32x4){0.f, 0.f, 0.f, 0.f};
#pragma unroll
    for (int s = 0; s < 2; ++s) {
#pragma unroll
        for (int t = 0; t < 4; ++t) {
            int row = t * 16 + r;
            int boff = row * 128 + (((s * 64) + g * 16) ^ ((row & 7) << 4));
            short8v ah = *(const short8v*)((const char*)As_h + boff);
            short8v al = *(const short8v*)((const char*)As_l + boff);
            acc[t] = __builtin_amdgcn_mfma_f32_16x16x32_bf16(ah, bh[s], acc[t], 0, 0, 0);
            acc[t] = __builtin_amdgcn_mfma_f32_16x16x32_bf16(al, bh[s], acc[t], 0, 0, 0);
            acc[t] = __builtin_amdgcn_mfma_f32_16x16x32_bf16(ah, bl[s], acc[t], 0, 0, 0);
        }
    }
    __syncthreads();   // all x-tile reads done

    // h epilogue (no relu) -> global pair + LDS tile (stride 256B, swizzled)
    {
        const float bbE = emb_b[col];
#pragma unroll
        for (int t = 0; t < 4; ++t) {
#pragma unroll
            for (int i = 0; i < 4; ++i) {
                int lrow = t * 16 + g * 4 + i;
                int grow = rb + lrow;
                float v = acc[t][i] + bbE;
                us hh = f2bf(v);
                us hl2 = f2bf(v - bf2f(hh));
                if (grow < nrows) {
                    size_t o = (size_t)grow * HD + col;
                    out_h[o] = hh; out_l[o] = hl2;
                }
                int byte = lrow * 256 + ((col * 2) ^ ((lrow & 7) << 4));
                *(us*)((char*)As_h + byte) = hh;
                *(us*)((char*)As_l + byte) = hl2;
            }
        }
    }
    __syncthreads();

    // stage-2 B regs: Wa (P cols) and Wb (Q cols), K=128
    short8v bPh[4], bPl[4], bQh[4], bQl[4];
    {
        size_t baseP = (size_t)col * 128 + (size_t)(g * 8);
        size_t baseQ = (size_t)(col + 128) * 128 + (size_t)(g * 8);
#pragma unroll
        for (int s = 0; s < 4; ++s) {
            bPh[s] = *(const short8v*)(wpqh + baseP + s * 32);
            bPl[s] = *(const short8v*)(wpql + baseP + s * 32);
            bQh[s] = *(const short8v*)(wpqh + baseQ + s * 32);
            bQl[s] = *(const short8v*)(wpql + baseQ + s * 32);
        }
    }

    f32x4 accP[4], accQ[4];
#pragma unroll
    for (int t = 0; t < 4; ++t) {
        accP[t] = (f32x4){0.f, 0.f, 0.f, 0.f};
        accQ[t] = (f32x4){0.f, 0.f, 0.f, 0.f};
    }
#pragma unroll
    for (int s = 0; s < 4; ++s) {
#pragma unroll
        for (int t = 0; t < 4; ++t) {
            int row = t * 16 + r;
            int boff = row * 256 + (((s * 64) + g * 16) ^ ((row & 7) << 4));
            short8v ah = *(const short8v*)((const char*)As_h + boff);
            short8v al = *(const short8v*)((const char*)As_l + boff);
            accP[t] = __builtin_amdgcn_mfma_f32_16x16x32_bf16(ah, bPh[s], accP[t], 0, 0, 0);
            accP[t] = __builtin_amdgcn_mfma_f32_16x16x32_bf16(al, bPh[s], accP[t], 0, 0, 0);
            accP[t] = __builtin_amdgcn_mfma_f32_16x16x32_bf16(ah, bPl[s], accP[t], 0, 0, 0);
            accQ[t] = __builtin_amdgcn_mfma_f32_16x16x32_bf16(ah, bQh[s], accQ[t], 0, 0, 0);
            accQ[t] = __builtin_amdgcn_mfma_f32_16x16x32_bf16(al, bQh[s], accQ[t], 0, 0, 0);
            accQ[t] = __builtin_amdgcn_mfma_f32_16x16x32_bf16(ah, bQl[s], accQ[t], 0, 0, 0);
        }
    }
    {
        const float bbP = b1msg[col];
#pragma unroll
        for (int t = 0; t < 4; ++t) {
#pragma unroll
            for (int i = 0; i < 4; ++i) {
                int row = rb + t * 16 + g * 4 + i;
                if (row >= nrows) continue;
                size_t o = (size_t)row * HD + col;
                Pb[o] = accP[t][i] + bbP;
                Qb[o] = accQ[t][i];
            }
        }
    }
}

// ---------------------------------------------------------------------------
// Fused update (+ next-layer PQ): U = relu([h|S]@Wcb + b1 + deg*bdeg);
// hout = relu(U@U2 + b2) -> global pair + LDS; [P|Q] = hout@[Wa|Wb]_{l+1}.
// ---------------------------------------------------------------------------
template<bool DOPQ>
__global__ __launch_bounds__(512) void k_updpq(
    const us* __restrict__ A1h, const us* __restrict__ A1l,   // h pair
    const us* __restrict__ A2h, const us* __restrict__ A2l,   // S pair
    const us* __restrict__ Wth, const us* __restrict__ Wtl,   // [128 j][256 k]
    const float* __restrict__ b1,
    const float* __restrict__ bdeg, const float* __restrict__ deg,
    const us* __restrict__ W2th, const us* __restrict__ W2tl, // [128 j][128 k]
    const float* __restrict__ b2,
    const us* __restrict__ wpqh, const us* __restrict__ wpql, // next layer [256 j][128 k]
    const float* __restrict__ b1msg,                          // next layer msg_b1
    us* __restrict__ out_h, us* __restrict__ out_l,
    float* __restrict__ Pb, float* __restrict__ Qb,
    int nrows)
{
    constexpr int K = 256;
    constexpr int CPR = K / 8;
    constexpr int ITER = (64 * CPR) / 512;
    __shared__ us As_h[64 * K];
    __shared__ us As_l[64 * K];

    const int tid  = threadIdx.x;
    const int wv   = tid >> 6;
    const int lane = tid & 63;
    const int r    = lane & 15;
    const int g    = lane >> 4;
    const int rb   = blockIdx.x * 64;
    const int col  = wv * 16 + r;

    // stage-1 B regs (Wcb, K=256)
    short8v bh[8], bl[8];
    {
        size_t wbase = (size_t)col * K + (size_t)(g * 8);
#pragma unroll
        for (int s = 0; s < 8; ++s) {
            bh[s] = *(const short8v*)(Wth + wbase + s * 32);
            bl[s] = *(const short8v*)(Wtl + wbase + s * 32);
        }
    }

    // stage A = [h|S], swizzled source
#pragma unroll
    for (int i = 0; i < ITER; ++i) {
        int f = tid + i * 512;
        int row = f / CPR, c = f % CPR;
        int grow = rb + row; if (grow >= nrows) grow = nrows - 1;
        int sb = (c * 16) ^ ((row & 7) << 4);
        const char *gh, *gl;
        if (sb < 256) {
            gh = (const char*)A1h + (size_t)grow * 256 + sb;
            gl = (const char*)A1l + (size_t)grow * 256 + sb;
        } else {
            gh = (const char*)A2h + (size_t)grow * 256 + (sb - 256);
            gl = (const char*)A2l + (size_t)grow * 256 + (sb - 256);
        }
        gload16(gh, (char*)As_h + (size_t)f * 16);
        gload16(gl, (char*)As_l + (size_t)f * 16);
    }
    __syncthreads();

    f32x4 acc[4];
#pragma unroll
    for (int t = 0; t < 4; ++t) acc[t] = (f32x4){0.f, 0.f, 0.f, 0.f};
#pragma unroll
    for (int s = 0; s < 8; ++s) {
#pragma unroll
        for (int t = 0; t < 4; ++t) {
            int row = t * 16 + r;
            int boff = row * (K * 2) + (((s * 64) + g * 16) ^ ((row & 7) << 4));
            short8v ah = *(const short8v*)((const char*)As_h + boff);
            short8v al = *(const short8v*)((const char*)As_l + boff);
            acc[t] = __builtin_amdgcn_mfma_f32_16x16x32_bf16(ah, bh[s], acc[t], 0, 0, 0);
            acc[t] = __builtin_amdgcn_mfma_f32_16x16x32_bf16(al, bh[s], acc[t], 0, 0, 0);
            acc[t] = __builtin_amdgcn_mfma_f32_16x16x32_bf16(ah, bl[s], acc[t], 0, 0, 0);
        }
    }
    __syncthreads();   // all [h|S] reads done

    // stage-2 B regs (U2, K=128)
    short8v b2h[4], b2l[4];
    {
        size_t wbase = (size_t)col * 128 + (size_t)(g * 8);
#pragma unroll
        for (int s = 0; s < 4; ++s) {
            b2h[s] = *(const short8v*)(W2th + wbase + s * 32);
            b2l[s] = *(const short8v*)(W2tl + wbase + s * 32);
        }
    }

    // U epilogue -> LDS tile (stride 256B, swizzled)
    {
        const float bb = b1[col];
        const float bd = bdeg[col];
#pragma unroll
        for (int t = 0; t < 4; ++t) {
#pragma unroll
            for (int i = 0; i < 4; ++i) {
                int lrow = t * 16 + g * 4 + i;
                int grow = rb + lrow;
                float dg = (grow < nrows) ? deg[grow] : 0.f;
                float v = acc[t][i] + bb + dg * bd;
                v = fmaxf(v, 0.f);
                us uh = f2bf(v);
                us ul = f2bf(v - bf2f(uh));
                int byte = lrow * 256 + ((col * 2) ^ ((lrow & 7) << 4));
                *(us*)((char*)As_h + byte) = uh;
                *(us*)((char*)As_l + byte) = ul;
            }
        }
    }
    __syncthreads();

    // stage 2: hout = relu(U @ U2 + b2)
    f32x4 acc2[4];
#pragma unroll
    for (int t = 0; t < 4; ++t) acc2[t] = (f32x4){0.f, 0.f, 0.f, 0.f};
#pragma unroll
    for (int s = 0; s < 4; ++s) {
#pragma unroll
        for (int t = 0; t < 4; ++t) {
            int row = t * 16 + r;
            int boff = row * 256 + (((s * 64) + g * 16) ^ ((row & 7) << 4));
            short8v ah = *(const short8v*)((const char*)As_h + boff);
            short8v al = *(const short8v*)((const char*)As_l + boff);
            acc2[t] = __builtin_amdgcn_mfma_f32_16x16x32_bf16(ah, b2h[s], acc2[t], 0, 0, 0);
            acc2[t] = __builtin_amdgcn_mfma_f32_16x16x32_bf16(al, b2h[s], acc2[t], 0, 0, 0);
            acc2[t] = __builtin_amdgcn_mfma_f32_16x16x32_bf16(ah, b2l[s], acc2[t], 0, 0, 0);
        }
    }
    if (!DOPQ) {
        const float bb2 = b2[col];
#pragma unroll
        for (int t = 0; t < 4; ++t) {
#pragma unroll
            for (int i = 0; i < 4; ++i) {
                int row = rb + t * 16 + g * 4 + i;
                if (row >= nrows) continue;
                float v = fmaxf(acc2[t][i] + bb2, 0.f);
                size_t o = (size_t)row * HD + col;
                us hh = f2bf(v);
                out_h[o] = hh;
                out_l[o] = f2bf(v - bf2f(hh));
            }
        }
        return;
    }

    __syncthreads();   // all U-tile reads done; safe to overwrite with h tile
    // hout epilogue -> global pair + LDS tile
    {
        const float bb2 = b2[col];
#pragma unroll
        for (int t = 0; t < 4; ++t) {
#pragma unroll
            for (int i = 0; i < 4; ++i) {
                int lrow = t * 16 + g * 4 + i;
                int grow = rb + lrow;
                float v = fmaxf(acc2[t][i] + bb2, 0.f);
                us hh = f2bf(v);
                us hl2 = f2bf(v - bf2f(hh));
                if (grow < nrows) {
                    size_t o = (size_t)grow * HD + col;
                    out_h[o] = hh; out_l[o] = hl2;
                }
                int byte = lrow * 256 + ((col * 2) ^ ((lrow & 7) << 4));
                *(us*)((char*)As_h + byte) = hh;
                *(us*)((char*)As_l + byte) = hl2;
            }
        }
    }
    __syncthreads();

    // stage 3: [P|Q] = hout @ [Wa|Wb] of NEXT layer
    short8v bPh[4], bPl[4], bQh[4], bQl[4];
    {
        size_t baseP = (size_t)col * 128 + (size_t)(g * 8);
        size_t baseQ = (size_t)(col + 128) * 128 + (size_t)(g * 8);
#pragma unroll
        for (int s = 0; s < 4; ++s) {
            bPh[s] = *(const short8v*)(wpqh + baseP + s * 32);
            bPl[s] = *(const short8v*)(wpql + baseP + s * 32);
            bQh[s] = *(const short8v*)(wpqh + baseQ + s * 32);
            bQl[s] = *(const short8v*)(wpql + baseQ + s * 32);
        }
    }
    f32x4 accP[4], accQ[4];
#pragma unroll
    for (int t = 0; t < 4; ++t) {
        accP[t] = (f32x4){0.f, 0.f, 0.f, 0.f};
        accQ[t] = (f32x4){0.f, 0.f, 0.f, 0.f};
    }
#pragma unroll
    for (int s = 0; s < 4; ++s) {
#pragma unroll
        for (int t = 0; t < 4; ++t) {
            int row = t * 16 + r;
            int boff = row * 256 + (((s * 64) + g * 16) ^ ((row & 7) << 4));
            short8v ah = *(const short8v*)((const char*)As_h + boff);
            short8v al = *(const short8v*)((const char*)As_l + boff);
            accP[t] = __builtin_amdgcn_mfma_f32_16x16x32_bf16(ah, bPh[s], accP[t], 0, 0, 0);
            accP[t] = __builtin_amdgcn_mfma_f32_16x16x32_bf16(al, bPh[s], accP[t], 0, 0, 0);
            accP[t] = __builtin_amdgcn_mfma_f32_16x16x32_bf16(ah, bPl[s], accP[t], 0, 0, 0);
            accQ[t] = __builtin_amdgcn_mfma_f32_16x16x32_bf16(ah, bQh[s], accQ[t], 0, 0, 0);
            accQ[t] = __builtin_amdgcn_mfma_f32_16x16x32_bf16(al, bQh[s], accQ[t], 0, 0, 0);
            accQ[t] = __builtin_amdgcn_mfma_f32_16x16x32_bf16(ah, bQl[s], accQ[t], 0, 0, 0);
        }
    }
    {
        const float bbP = b1msg[col];
#pragma unroll
        for (int t = 0; t < 4; ++t) {
#pragma unroll
            for (int i = 0; i < 4; ++i) {
                int row = rb + t * 16 + g * 4 + i;
                if (row >= nrows) continue;
                size_t o = (size_t)row * HD + col;
                Pb[o] = accP[t][i] + bbP;
                Qb[o] = accQ[t][i];
            }
        }
    }
}

// ---------------------------------------------------------------------------
// Conversions
// ---------------------------------------------------------------------------
__global__ void k_cvtA(const float* __restrict__ src,
                       us* __restrict__ dh, us* __restrict__ dl, long n)
{
    long i = (long)blockIdx.x * blockDim.x + threadIdx.x;
    if (i >= n) return;
    float v = src[i];
    us h = f2bf(v);
    dh[i] = h;
    dl[i] = f2bf(v - bf2f(h));
}

__global__ void k_cvtW(const float* __restrict__ src, long sstride, int K,
                       us* __restrict__ dh, us* __restrict__ dl, long dstride)
{
    int l = blockIdx.y;
    int idx = blockIdx.x * 256 + threadIdx.x;
    if (idx >= K * 128) return;
    int k = idx >> 7, j = idx & 127;
    float v = src[(size_t)l * sstride + (size_t)k * 128 + j];
    us h = f2bf(v);
    size_t o = (size_t)l * dstride + (size_t)j * K + k;
    dh[o] = h;
    dl[o] = f2bf(v - bf2f(h));
}

__global__ void k_cvtW2(const float* __restrict__ srcA, long strideA,
                        const float* __restrict__ srcB, long strideB,
                        int K1s, int K,
                        us* __restrict__ dh, us* __restrict__ dl, long dstride)
{
    int l = blockIdx.y;
    int idx = blockIdx.x * 256 + threadIdx.x;
    if (idx >= K * 128) return;
    int k = idx >> 7, j = idx & 127;
    float v = (k < K1s)
        ? srcA[(size_t)l * strideA + (size_t)k * 128 + j]
        : srcB[(size_t)l * strideB + (size_t)(k - K1s) * 128 + j];
    us h = f2bf(v);
    size_t o = (size_t)l * dstride + (size_t)j * K + k;
    dh[o] = h;
    dl[o] = f2bf(v - bf2f(h));
}

// ---------------------------------------------------------------------------
// CSR build: deg+hist -> 3-phase parallel scan -> scatter (fused ea permute)
// ---------------------------------------------------------------------------
__global__ void k_deghist(const int* __restrict__ dst, int* __restrict__ degi, int E,
                          const int* __restrict__ batch, int* __restrict__ gcnt, int N)
{
    int i = blockIdx.x * blockDim.x + threadIdx.x;
    if (i < E) atomicAdd(&degi[dst[i]], 1);
    if (i < N) atomicAdd(&gcnt[batch[i]], 1);
}

__global__ __launch_bounds__(256) void k_scan1(const int* __restrict__ degi,
                                               int* __restrict__ thrpre,
                                               int* __restrict__ bsum, int N)
{
    __shared__ int sc[256];
    const int t = threadIdx.x, b = blockIdx.x;
    int i0 = b * SCB + t * 8;
    int s = 0;
#pragma unroll
    for (int q = 0; q < 8; ++q) {
        int i = i0 + q;
        if (i < N) s += degi[i];
    }
    sc[t] = s;
    __syncthreads();
    for (int o = 1; o < 256; o <<= 1) {
        int v = (t >= o) ? sc[t - o] : 0;
        __syncthreads();
        sc[t] += v;
        __syncthreads();
    }
    thrpre[b * 256 + t] = sc[t] - s;
    if (t == 255) bsum[b] = sc[255];
}

__global__ void k_scan2(const int* __restrict__ bsum, int* __restrict__ boff, int nb)
{
    if (threadIdx.x == 0 && blockIdx.x == 0) {
        int run = 0;
        for (int b = 0; b < nb; ++b) { boff[b] = run; run += bsum[b]; }
    }
}

__global__ __launch_bounds__(256) void k_scan3(
    const int* __restrict__ degi, const int* __restrict__ thrpre,
    const int* __restrict__ boff,
    int* __restrict__ rowptr, int* __restrict__ cursor,
    float* __restrict__ degf, int N, int E)
{
    const int t = threadIdx.x, b = blockIdx.x;
    int run = boff[b] + thrpre[b * 256 + t];
    int i0 = b * SCB + t * 8;
#pragma unroll
    for (int q = 0; q < 8; ++q) {
        int i = i0 + q;
        if (i < N) {
            int d = degi[i];
            rowptr[i] = run;
            cursor[i] = run;
            degf[i] = (float)d;
            run += d;
        }
    }
    if (b == 0 && t == 0) rowptr[N] = E;
}

__global__ void k_scatter(const int* __restrict__ dst, const int* __restrict__ src,
                          int* __restrict__ cursor,
                          const float* __restrict__ ea,
                          int* __restrict__ csr_src, int* __restrict__ csr_eid,
                          float* __restrict__ ea_p, int E)
{
    int e = blockIdx.x * blockDim.x + threadIdx.x;
    if (e >= E) return;
    int d = dst[e];
    int pos = atomicAdd(&cursor[d], 1);
    csr_src[pos] = src[e];
    if (ea_p) {
        const float4* s4 = (const float4*)&ea[(size_t)e * 16];
        float4* d4 = (float4*)&ea_p[(size_t)pos * 16];
        d4[0] = s4[0]; d4[1] = s4[1]; d4[2] = s4[2]; d4[3] = s4[3];
    } else {
        csr_eid[pos] = e;
    }
}

// ---------------------------------------------------------------------------
// Weight folds: fold = W2 @ U1b ; bvec2 = b2 @ U1b
// ---------------------------------------------------------------------------
__global__ __launch_bounds__(256) void k_foldW(
    const float* __restrict__ msg_W2, const float* __restrict__ upd_W1,
    float* __restrict__ fold)
{
    int l = blockIdx.x >> 3, rb = blockIdx.x & 7;
    const float* W2  = msg_W2 + (size_t)l * HD * HD;
    const float* U1b = upd_W1 + (size_t)l * 256 * HD + (size_t)HD * HD;
    float* Wout = fold + (size_t)l * HD * HD;
    int j = threadIdx.x & 127;
    int rh = threadIdx.x >> 7;
    int r0 = rb * 16 + rh * 8;
    float acc[8] = {0.f,0.f,0.f,0.f,0.f,0.f,0.f,0.f};
    for (int k = 0; k < HD; ++k) {
        float u = U1b[(size_t)k * HD + j];
#pragma unroll
        for (int rr = 0; rr < 8; ++rr)
            acc[rr] = fmaf(W2[(size_t)(r0 + rr) * HD + k], u, acc[rr]);
    }
#pragma unroll
    for (int rr = 0; rr < 8; ++rr)
        Wout[(size_t)(r0 + rr) * HD + j] = acc[rr];
}

__global__ __launch_bounds__(128) void k_foldb(
    const float* __restrict__ msg_b2, const float* __restrict__ upd_W1,
    float* __restrict__ bvec2)
{
    int l = blockIdx.x, j = threadIdx.x;
    const float* U1b = upd_W1 + (size_t)l * 256 * HD + (size_t)HD * HD;
    const float* b2 = msg_b2 + (size_t)l * HD;
    float acc = 0.f;
    for (int k = 0; k < HD; ++k) acc = fmaf(b2[k], U1b[(size_t)k * HD + j], acc);
    bvec2[(size_t)l * HD + j] = acc;
}

// ---------------------------------------------------------------------------
// Edge gather: S[n] = sum_{e:dst=n} relu(P[n] + Q[src] + ea@Wc)
// Wave per node, 2 dims/lane, 16-edge CLAMPED batch.
// ---------------------------------------------------------------------------
#define EB 16
template<bool PERM>
__global__ __launch_bounds__(256) void k_edge(
    const float* __restrict__ P, const float* __restrict__ Q,
    const float* __restrict__ EA,
    const int* __restrict__ rowptr,
    const int* __restrict__ csr_src, const int* __restrict__ csr_eid,
    const float* __restrict__ W1c,
    us* __restrict__ Sh, us* __restrict__ Sl, int N)
{
    const int lane = threadIdx.x & 63;
    const int node = __builtin_amdgcn_readfirstlane(blockIdx.x * 4 + (threadIdx.x >> 6));
    if (node >= N) return;
    float wA[16], wB[16];
#pragma unroll
    for (int k = 0; k < 16; ++k) {
        wA[k] = W1c[k * HD + lane];
        wB[k] = W1c[k * HD + 64 + lane];
    }
    const int beg = __builtin_amdgcn_readfirstlane(rowptr[node]);
    const int end = __builtin_amdgcn_readfirstlane(rowptr[node + 1]);
    const float pA = P[(size_t)node * HD + lane];
    const float pB = P[(size_t)node * HD + 64 + lane];
    float accA = 0.f, accB = 0.f;

    for (int i = beg; i < end; i += EB) {
        int myi = i + (lane & 15);
        myi = (myi < end) ? myi : (end - 1);
        int myidx = PERM ? myi : csr_eid[myi];
        int mysrc = csr_src[myi];
        int sv[EB], ei[EB];
#pragma unroll
        for (int r = 0; r < EB; ++r) {
            sv[r] = __builtin_amdgcn_readlane(mysrc, r);
            ei[r] = PERM ? 0 : __builtin_amdgcn_readlane(myidx, r);
        }
        float qA[EB], qB[EB];
#pragma unroll
        for (int r = 0; r < EB; ++r) {
            qA[r] = Q[(size_t)sv[r] * HD + lane];
            qB[r] = Q[(size_t)sv[r] * HD + 64 + lane];
        }
#pragma unroll
        for (int r = 0; r < EB; ++r) {
            int ii = i + r; ii = (ii < end) ? ii : (end - 1);
            const float4* Ev = PERM ? (const float4*)&EA[(size_t)ii * 16]
                                    : (const float4*)&EA[(size_t)ei[r] * 16];
            float4 v0 = Ev[0], v1 = Ev[1], v2 = Ev[2], v3 = Ev[3];
            float tA = pA + qA[r], tB = pB + qB[r];
            tA = fmaf(v0.x, wA[0],  tA); tB = fmaf(v0.x, wB[0],  tB);
            tA = fmaf(v0.y, wA[1],  tA); tB = fmaf(v0.y, wB[1],  tB);
            tA = fmaf(v0.z, wA[2],  tA); tB = fmaf(v0.z, wB[2],  tB);
            tA = fmaf(v0.w, wA[3],  tA); tB = fmaf(v0.w, wB[3],  tB);
            tA = fmaf(v1.x, wA[4],  tA); tB = fmaf(v1.x, wB[4],  tB);
            tA = fmaf(v1.y, wA[5],  tA); tB = fmaf(v1.y, wB[5],  tB);
            tA = fmaf(v1.z, wA[6],  tA); tB = fmaf(v1.z, wB[6],  tB);
            tA = fmaf(v1.w, wA[7],  tA); tB = fmaf(v1.w, wB[7],  tB);
            tA = fmaf(v2.x, wA[8],  tA); tB = fmaf(v2.x, wB[8],  tB);
            tA = fmaf(v2.y, wA[9],  tA); tB = fmaf(v2.y, wB[9],  tB);
            tA = fmaf(v2.z, wA[10], tA); tB = fmaf(v2.z, wB[10], tB);
            tA = fmaf(v2.w, wA[11], tA); tB = fmaf(v2.w, wB[11], tB);
            tA = fmaf(v3.x, wA[12], tA); tB = fmaf(v3.x, wB[12], tB);
            tA = fmaf(v3.y, wA[13], tA); tB = fmaf(v3.y, wB[13], tB);
            tA = fmaf(v3.z, wA[14], tA); tB = fmaf(v3.z, wB[14], tB);
            tA = fmaf(v3.w, wA[15], tA); tB = fmaf(v3.w, wB[15], tB);
            bool ok = (i + r) < end;
            accA += ok ? fmaxf(tA, 0.f) : 0.f;
            accB += ok ? fmaxf(tB, 0.f) : 0.f;
        }
    }
    size_t oA = (size_t)node * HD + lane;
    size_t oB = oA + 64;
    us hA = f2bf(accA);
    us hB = f2bf(accB);
    Sh[oA] = hA; Sl[oA] = f2bf(accA - bf2f(hA));
    Sh[oB] = hB; Sl[oB] = f2bf(accB - bf2f(hB));
}

// ---------------------------------------------------------------------------
// Pool (segment mean/max over sorted batch) from bf16 hi/lo h; then classifier.
// ---------------------------------------------------------------------------
__global__ __launch_bounds__(256) void k_pool2(
    const us* __restrict__ hh, const us* __restrict__ hl,
    const int* __restrict__ batch,
    float* __restrict__ gsum, unsigned int* __restrict__ gmax, int N)
{
    int nchunk = (N + gridDim.x - 1) / gridDim.x;
    int n0 = blockIdx.x * nchunk;
    int n1 = n0 + nchunk; if (n1 > N) n1 = N;
    int j = threadIdx.x & 127;
    int half = threadIdx.x >> 7;
    float s = 0.f, m = 0.f; int gcur = -1;
    for (int n = n0 + half; n < n1; n += 2) {
        int g = batch[n];
        if (g != gcur) {
            if (gcur >= 0) {
                atomicAdd(&gsum[(size_t)gcur * HD + j], s);
                atomicMax(&gmax[(size_t)gcur * HD + j], __float_as_uint(m));
            }
            gcur = g; s = 0.f; m = 0.f;
        }
        size_t o = (size_t)n * HD + j;
        float v = bf2f(hh[o]) + bf2f(hl[o]);
        s += v; m = fmaxf(m, v);
    }
    if (gcur >= 0) {
        atomicAdd(&gsum[(size_t)gcur * HD + j], s);
        atomicMax(&gmax[(size_t)gcur * HD + j], __float_as_uint(m));
    }
}

__global__ __launch_bounds__(128) void k_cls(
    const float* __restrict__ gsum, const float* __restrict__ gmax,
    const int* __restrict__ gcnt,
    const float* __restrict__ W1, const float* __restrict__ b1,
    const float* __restrict__ W2, const float* __restrict__ b2,
    const float* __restrict__ W3, const float* __restrict__ b3,
    float* __restrict__ out)
{
    __shared__ float rep[256];
    __shared__ float z1[128];
    __shared__ float z2[64];
    const int g = blockIdx.x;
    const int j = threadIdx.x;
    float cntf = (float)gcnt[g];
    rep[j]       = gsum[(size_t)g * HD + j] / fmaxf(cntf, 1.f);
    rep[128 + j] = gmax[(size_t)g * HD + j];
    __syncthreads();
    float a = 0.f;
    for (int k = 0; k < 256; ++k) a = fmaf(rep[k], W1[(size_t)k * 128 + j], a);
    z1[j] = fmaxf(a + b1[j], 0.f);
    __syncthreads();
    if (j < 64) {
        float b = 0.f;
        for (int k = 0; k < 128; ++k) b = fmaf(z1[k], W2[(size_t)k * 64 + j], b);
        z2[j] = fmaxf(b + b2[j], 0.f);
    }
    __syncthreads();
    if (j < 2) {
        float c = 0.f;
        for (int k = 0; k < 64; ++k) c = fmaf(z2[k], W3[(size_t)k * 2 + j], c);
        out[(size_t)g * 2 + j] = c + b3[j];
    }
}

extern "C" void kernel_launch(void* const* d_in, const int* in_sizes, int n_in,
                              void* d_out, int out_size, void* d_ws, size_t ws_size,
                              hipStream_t stream) {
    const float* x      = (const float*)d_in[0];
    const float* ea     = (const float*)d_in[1];
    const int*   ei     = (const int*)d_in[2];
    const int*   batch  = (const int*)d_in[3];
    const float* emb_W  = (const float*)d_in[4];
    const float* emb_b  = (const float*)d_in[5];
    const float* msg_W1 = (const float*)d_in[6];
    const float* msg_b1 = (const float*)d_in[7];
    const float* msg_W2 = (const float*)d_in[8];
    const float* msg_b2 = (const float*)d_in[9];
    const float* upd_W1 = (const float*)d_in[10];
    const float* upd_b1 = (const float*)d_in[11];
    const float* upd_W2 = (const float*)d_in[12];
    const float* upd_b2 = (const float*)d_in[13];
    const float* cW1 = (const float*)d_in[14];
    const float* cb1 = (const float*)d_in[15];
    const float* cW2 = (const float*)d_in[16];
    const float* cb2 = (const float*)d_in[17];
    const float* cW3 = (const float*)d_in[18];
    const float* cb3 = (const float*)d_in[19];

    const int N = in_sizes[0] / 64;
    const int E = in_sizes[1] / 16;
    const int G = 256, L = 3;
    const int* src = ei;
    const int* dst = ei + E;
    const int nb = (N + SCB - 1) / SCB;

    char* w = (char*)d_ws;
    size_t off = 0;
    auto alloc = [&](size_t bytes) -> void* {
        void* p = w + off;
        off += (bytes + 255) & ~(size_t)255;
        return p;
    };
    float* Pb  = (float*)alloc((size_t)N * HD * 4);  // P fp32
    float* Qb  = (float*)alloc((size_t)N * HD * 4);  // Q fp32
    us* S_h = (us*)alloc((size_t)N * HD * 2);        // S hi; aliased as x_h
    us* S_l = (us*)alloc((size_t)N * HD * 2);        // S lo; aliased as x_l
    us* h_h = (us*)alloc((size_t)N * HD * 2);
    us* h_l = (us*)alloc((size_t)N * HD * 2);
    us* x_h = S_h;                                   // alias: x pair over S pair
    us* x_l = S_l;
    float* fold  = (float*)alloc((size_t)L * HD * HD * 4);
    float* bvec2 = (float*)alloc((size_t)L * HD * 4);
    us* embt_h = (us*)alloc((size_t)128 * 64 * 2);
    us* embt_l = (us*)alloc((size_t)128 * 64 * 2);
    us* WPQt_h = (us*)alloc((size_t)L * 256 * 128 * 2);  // [256 j][128 k]
    us* WPQt_l = (us*)alloc((size_t)L * 256 * 128 * 2);
    us* Wcbt_h = (us*)alloc((size_t)L * 128 * 256 * 2);  // [128 j][256 k]
    us* Wcbt_l = (us*)alloc((size_t)L * 128 * 256 * 2);
    us* U2t_h  = (us*)alloc((size_t)L * 128 * 128 * 2);
    us* U2t_l  = (us*)alloc((size_t)L * 128 * 128 * 2);
    int*   degi   = (int*)alloc((size_t)N * 4);
    float* degf   = (float*)alloc((size_t)N * 4);
    int*   rowptr = (int*)alloc((size_t)(N + 1) * 4);
    int*   cursor = (int*)alloc((size_t)N * 4);
    int*   thrpre = (int*)alloc((size_t)nb * 256 * 4);
    int*   bsum   = (int*)alloc((size_t)(nb + 1) * 4);
    int*   boff   = (int*)alloc((size_t)(nb + 1) * 4);
    int*   gcnt   = (int*)alloc(256 * 4);
    float* gsum   = (float*)alloc((size_t)G * HD * 4);
    float* gmax   = (float*)alloc((size_t)G * HD * 4);
    int*   csr_src = (int*)alloc((size_t)E * 4);
    int*   csr_eid = (int*)alloc((size_t)E * 4);
    float* ea_p = nullptr;
    if (ws_size && off + (size_t)E * 16 * 4 + 256 <= ws_size)
        ea_p = (float*)alloc((size_t)E * 16 * 4);
    (void)n_in; (void)out_size;

    hipMemsetAsync(degi, 0, (size_t)N * 4, stream);
    hipMemsetAsync(gcnt, 0, 256 * 4, stream);
    hipMemsetAsync(gsum, 0, (size_t)G * HD * 4, stream);
    hipMemsetAsync(gmax, 0, (size_t)G * HD * 4, stream);

    // ---- CSR build (parallel scan; scatter fuses ea permutation) ----
    int mEN = (E > N ? E : N);
    k_deghist<<<(mEN + 255) / 256, 256, 0, stream>>>(dst, degi, E, batch, gcnt, N);
    k_scan1<<<nb, 256, 0, stream>>>(degi, thrpre, bsum, N);
    k_scan2<<<1, 64, 0, stream>>>(bsum, boff, nb);
    k_scan3<<<nb, 256, 0, stream>>>(degi, thrpre, boff, rowptr, cursor, degf, N, E);
    k_scatter<<<(E + 255) / 256, 256, 0, stream>>>(dst, src, cursor, ea,
                                                   csr_src, csr_eid, ea_p, E);

    // ---- weight folds + conversions ----
    k_foldW<<<L * 8, 256, 0, stream>>>(msg_W2, upd_W1, fold);
    k_foldb<<<L, 128, 0, stream>>>(msg_b2, upd_W1, bvec2);

    k_cvtA<<<(int)(((long)N * 64 + 255) / 256), 256, 0, stream>>>(x, x_h, x_l, (long)N * 64);
    k_cvtW<<<dim3(32, 1), 256, 0, stream>>>(emb_W, 0, 64, embt_h, embt_l, 0);
    k_cvtW<<<dim3(64, L), 256, 0, stream>>>(msg_W1, 272 * 128, 128,
                                            WPQt_h, WPQt_l, 256 * 128);
    k_cvtW<<<dim3(64, L), 256, 0, stream>>>(msg_W1 + 128 * 128, 272 * 128, 128,
                                            WPQt_h + 128 * 128, WPQt_l + 128 * 128,
                                            256 * 128);
    k_cvtW2<<<dim3(128, L), 256, 0, stream>>>(upd_W1, 256 * 128, fold, 128 * 128,
                                              128, 256, Wcbt_h, Wcbt_l, 128 * 256);
    k_cvtW<<<dim3(64, L), 256, 0, stream>>>(upd_W2, 128 * 128, 128,
                                            U2t_h, U2t_l, 128 * 128);

    const int gb = (N + 63) / 64;
    // ---- fused embed + layer-0 PQ ----
    k_embpq<<<gb, 512, 0, stream>>>(x_h, x_l, embt_h, embt_l, emb_b,
                                    WPQt_h, WPQt_l, msg_b1,
                                    h_h, h_l, Pb, Qb, N);

    for (int l = 0; l < L; ++l) {
        const float* W1 = msg_W1 + (size_t)l * 272 * HD;
        // S[n] = sum_in relu(P[n] + Q[src] + ea@Wc) -> bf16 pair
        if (ea_p)
            k_edge<true><<<(N + 3) / 4, 256, 0, stream>>>(Pb, Qb, ea_p, rowptr,
                                                          csr_src, nullptr,
                                                          W1 + 256 * HD, S_h, S_l, N);
        else
            k_edge<false><<<(N + 3) / 4, 256, 0, stream>>>(Pb, Qb, ea, rowptr,
                                                           csr_src, csr_eid,
                                                           W1 + 256 * HD, S_h, S_l, N);
        // fused update (+ next-layer PQ for l < L-1)
        if (l < L - 1)
            k_updpq<true><<<gb, 512, 0, stream>>>(
                h_h, h_l, S_h, S_l,
                Wcbt_h + (size_t)l * 128 * 256, Wcbt_l + (size_t)l * 128 * 256,
                upd_b1 + (size_t)l * HD, bvec2 + (size_t)l * HD, degf,
                U2t_h + (size_t)l * 128 * 128, U2t_l + (size_t)l * 128 * 128,
                upd_b2 + (size_t)l * HD,
                WPQt_h + (size_t)(l + 1) * 256 * 128,
                WPQt_l + (size_t)(l + 1) * 256 * 128,
                msg_b1 + (size_t)(l + 1) * HD,
                h_h, h_l, Pb, Qb, N);
        else
            k_updpq<false><<<gb, 512, 0, stream>>>(
                h_h, h_l, S_h, S_l,
                Wcbt_h + (size_t)l * 128 * 256, Wcbt_l + (size_t)l * 128 * 256,
                upd_b1 + (size_t)l * HD, bvec2 + (size_t)l * HD, degf,
                U2t_h + (size_t)l * 128 * 128, U2t_l + (size_t)l * 128 * 128,
                upd_b2 + (size_t)l * HD,
                nullptr, nullptr, nullptr,
                h_h, h_l, nullptr, nullptr, N);
    }

    k_pool2<<<1024, 256, 0, stream>>>(h_h, h_l, batch, gsum, (unsigned int*)gmax, N);
    k_cls<<<G, 128, 0, stream>>>(gsum, gmax, gcnt, cW1, cb1, cW2, cb2, cW3, cb3,
                                 (float*)d_out);
}

// Round 17
// 649.681 us; speedup vs baseline: 1.1159x; 1.0262x over previous
//
#include <hip/hip_runtime.h>
#include <hip/hip_bf16.h>

#define HD 128
#define SCB 2048   // elements per scan block

typedef __attribute__((ext_vector_type(8))) short short8v;
typedef __attribute__((ext_vector_type(4))) float f32x4;
typedef unsigned short us;

__device__ __forceinline__ us f2bf(float f) {
    union { float f; unsigned u; } c; c.f = f;
    unsigned u = c.u;
    return (us)((u + 0x7fffu + ((u >> 16) & 1u)) >> 16);
}
__device__ __forceinline__ float bf2f(us b) {
    union { unsigned u; float f; } c; c.u = ((unsigned)b) << 16;
    return c.f;
}

// async global->LDS, 16B per lane; LDS dest must be wave-uniform base + lane*16
__device__ __forceinline__ void gload16(const void* g, void* l) {
    __builtin_amdgcn_global_load_lds(
        (const __attribute__((address_space(1))) unsigned int*)g,
        (__attribute__((address_space(3))) unsigned int*)l,
        16, 0, 0);
}

// ---------------------------------------------------------------------------
// Fused embed+PQ: h = x@embW + emb_b (K=64); [P|Q] = h@[Wa|Wb] (+b1 on P).
// Block 512 thr = 8 waves, 64-row tile. h tile chained through LDS.
// ---------------------------------------------------------------------------
__global__ __launch_bounds__(512) void k_embpq(
    const us* __restrict__ xh, const us* __restrict__ xl,
    const us* __restrict__ embth, const us* __restrict__ embtl, // [128 j][64 k]
    const float* __restrict__ emb_b,
    const us* __restrict__ wpqh, const us* __restrict__ wpql,   // [256 j][128 k]
    const float* __restrict__ b1msg,
    us* __restrict__ out_h, us* __restrict__ out_l,
    float* __restrict__ Pb, float* __restrict__ Qb, int nrows)
{
    __shared__ us As_h[8192];   // 16KB: x tile (row*128B), then h tile (row*256B)
    __shared__ us As_l[8192];

    const int tid  = threadIdx.x;
    const int wv   = tid >> 6;
    const int lane = tid & 63;
    const int r    = lane & 15;
    const int g    = lane >> 4;
    const int rb   = blockIdx.x * 64;
    const int col  = wv * 16 + r;

    // stage-1 B regs (embW, K=64)
    short8v bh[2], bl[2];
    {
        size_t wbase = (size_t)col * 64 + (size_t)(g * 8);
#pragma unroll
        for (int s = 0; s < 2; ++s) {
            bh[s] = *(const short8v*)(embth + wbase + s * 32);
            bl[s] = *(const short8v*)(embtl + wbase + s * 32);
        }
    }

    // stage x pair: 64 rows x 8 chunks = 512 (1 per thread), swizzled source
    {
        int f = tid;
        int row = f >> 3, c = f & 7;
        int grow = rb + row; if (grow >= nrows) grow = nrows - 1;
        int sb = (c * 16) ^ ((row & 7) << 4);
        gload16((const char*)xh + (size_t)grow * 128 + sb, (char*)As_h + (size_t)f * 16);
        gload16((const char*)xl + (size_t)grow * 128 + sb, (char*)As_l + (size_t)f * 16);
    }
    __syncthreads();

    f32x4 acc[4];
#pragma unroll
    for (int t = 0; t < 4; ++t) acc[t] = (f32x4){0.f, 0.f, 0.f, 0.f};
#pragma unroll
    for (int s = 0; s < 2; ++s) {
#pragma unroll
        for (int t = 0; t < 4; ++t) {
            int row = t * 16 + r;
            int boff = row * 128 + (((s * 64) + g * 16) ^ ((row & 7) << 4));
            short8v ah = *(const short8v*)((const char*)As_h + boff);
            short8v al = *(const short8v*)((const char*)As_l + boff);
            acc[t] = __builtin_amdgcn_mfma_f32_16x16x32_bf16(ah, bh[s], acc[t], 0, 0, 0);
            acc[t] = __builtin_amdgcn_mfma_f32_16x16x32_bf16(al, bh[s], acc[t], 0, 0, 0);
            acc[t] = __builtin_amdgcn_mfma_f32_16x16x32_bf16(ah, bl[s], acc[t], 0, 0, 0);
        }
    }
    __syncthreads();   // all x-tile reads done

    // h epilogue (no relu) -> global pair + LDS tile (stride 256B, swizzled)
    {
        const float bbE = emb_b[col];
#pragma unroll
        for (int t = 0; t < 4; ++t) {
#pragma unroll
            for (int i = 0; i < 4; ++i) {
                int lrow = t * 16 + g * 4 + i;
                int grow = rb + lrow;
                float v = acc[t][i] + bbE;
                us hh = f2bf(v);
                us hl2 = f2bf(v - bf2f(hh));
                if (grow < nrows) {
                    size_t o = (size_t)grow * HD + col;
                    out_h[o] = hh; out_l[o] = hl2;
                }
                int byte = lrow * 256 + ((col * 2) ^ ((lrow & 7) << 4));
                *(us*)((char*)As_h + byte) = hh;
                *(us*)((char*)As_l + byte) = hl2;
            }
        }
    }
    __syncthreads();

    // stage-2 B regs: Wa (P cols) and Wb (Q cols), K=128
    short8v bPh[4], bPl[4], bQh[4], bQl[4];
    {
        size_t baseP = (size_t)col * 128 + (size_t)(g * 8);
        size_t baseQ = (size_t)(col + 128) * 128 + (size_t)(g * 8);
#pragma unroll
        for (int s = 0; s < 4; ++s) {
            bPh[s] = *(const short8v*)(wpqh + baseP + s * 32);
            bPl[s] = *(const short8v*)(wpql + baseP + s * 32);
            bQh[s] = *(const short8v*)(wpqh + baseQ + s * 32);
            bQl[s] = *(const short8v*)(wpql + baseQ + s * 32);
        }
    }

    f32x4 accP[4], accQ[4];
#pragma unroll
    for (int t = 0; t < 4; ++t) {
        accP[t] = (f32x4){0.f, 0.f, 0.f, 0.f};
        accQ[t] = (f32x4){0.f, 0.f, 0.f, 0.f};
    }
#pragma unroll
    for (int s = 0; s < 4; ++s) {
#pragma unroll
        for (int t = 0; t < 4; ++t) {
            int row = t * 16 + r;
            int boff = row * 256 + (((s * 64) + g * 16) ^ ((row & 7) << 4));
            short8v ah = *(const short8v*)((const char*)As_h + boff);
            short8v al = *(const short8v*)((const char*)As_l + boff);
            accP[t] = __builtin_amdgcn_mfma_f32_16x16x32_bf16(ah, bPh[s], accP[t], 0, 0, 0);
            accP[t] = __builtin_amdgcn_mfma_f32_16x16x32_bf16(al, bPh[s], accP[t], 0, 0, 0);
            accP[t] = __builtin_amdgcn_mfma_f32_16x16x32_bf16(ah, bPl[s], accP[t], 0, 0, 0);
            accQ[t] = __builtin_amdgcn_mfma_f32_16x16x32_bf16(ah, bQh[s], accQ[t], 0, 0, 0);
            accQ[t] = __builtin_amdgcn_mfma_f32_16x16x32_bf16(al, bQh[s], accQ[t], 0, 0, 0);
            accQ[t] = __builtin_amdgcn_mfma_f32_16x16x32_bf16(ah, bQl[s], accQ[t], 0, 0, 0);
        }
    }
    {
        const float bbP = b1msg[col];
#pragma unroll
        for (int t = 0; t < 4; ++t) {
#pragma unroll
            for (int i = 0; i < 4; ++i) {
                int row = rb + t * 16 + g * 4 + i;
                if (row >= nrows) continue;
                size_t o = (size_t)row * HD + col;
                Pb[o] = accP[t][i] + bbP;
                Qb[o] = accQ[t][i];
            }
        }
    }
}

// ---------------------------------------------------------------------------
// Fused update (+ next-layer PQ): U = relu([h|S]@Wcb + b1 + deg*bdeg);
// hout = relu(U@U2 + b2) -> global pair + LDS; [P|Q] = hout@[Wa|Wb]_{l+1}.
// ---------------------------------------------------------------------------
template<bool DOPQ>
__global__ __launch_bounds__(512) void k_updpq(
    const us* __restrict__ A1h, const us* __restrict__ A1l,   // h pair
    const us* __restrict__ A2h, const us* __restrict__ A2l,   // S pair
    const us* __restrict__ Wth, const us* __restrict__ Wtl,   // [128 j][256 k]
    const float* __restrict__ b1,
    const float* __restrict__ bdeg, const float* __restrict__ deg,
    const us* __restrict__ W2th, const us* __restrict__ W2tl, // [128 j][128 k]
    const float* __restrict__ b2,
    const us* __restrict__ wpqh, const us* __restrict__ wpql, // next layer [256 j][128 k]
    const float* __restrict__ b1msg,                          // next layer msg_b1
    us* __restrict__ out_h, us* __restrict__ out_l,
    float* __restrict__ Pb, float* __restrict__ Qb,
    int nrows)
{
    constexpr int K = 256;
    constexpr int CPR = K / 8;
    constexpr int ITER = (64 * CPR) / 512;
    __shared__ us As_h[64 * K];
    __shared__ us As_l[64 * K];

    const int tid  = threadIdx.x;
    const int wv   = tid >> 6;
    const int lane = tid & 63;
    const int r    = lane & 15;
    const int g    = lane >> 4;
    const int rb   = blockIdx.x * 64;
    const int col  = wv * 16 + r;

    // stage-1 B regs (Wcb, K=256)
    short8v bh[8], bl[8];
    {
        size_t wbase = (size_t)col * K + (size_t)(g * 8);
#pragma unroll
        for (int s = 0; s < 8; ++s) {
            bh[s] = *(const short8v*)(Wth + wbase + s * 32);
            bl[s] = *(const short8v*)(Wtl + wbase + s * 32);
        }
    }

    // stage A = [h|S], swizzled source
#pragma unroll
    for (int i = 0; i < ITER; ++i) {
        int f = tid + i * 512;
        int row = f / CPR, c = f % CPR;
        int grow = rb + row; if (grow >= nrows) grow = nrows - 1;
        int sb = (c * 16) ^ ((row & 7) << 4);
        const char *gh, *gl;
        if (sb < 256) {
            gh = (const char*)A1h + (size_t)grow * 256 + sb;
            gl = (const char*)A1l + (size_t)grow * 256 + sb;
        } else {
            gh = (const char*)A2h + (size_t)grow * 256 + (sb - 256);
            gl = (const char*)A2l + (size_t)grow * 256 + (sb - 256);
        }
        gload16(gh, (char*)As_h + (size_t)f * 16);
        gload16(gl, (char*)As_l + (size_t)f * 16);
    }
    __syncthreads();

    f32x4 acc[4];
#pragma unroll
    for (int t = 0; t < 4; ++t) acc[t] = (f32x4){0.f, 0.f, 0.f, 0.f};
#pragma unroll
    for (int s = 0; s < 8; ++s) {
#pragma unroll
        for (int t = 0; t < 4; ++t) {
            int row = t * 16 + r;
            int boff = row * (K * 2) + (((s * 64) + g * 16) ^ ((row & 7) << 4));
            short8v ah = *(const short8v*)((const char*)As_h + boff);
            short8v al = *(const short8v*)((const char*)As_l + boff);
            acc[t] = __builtin_amdgcn_mfma_f32_16x16x32_bf16(ah, bh[s], acc[t], 0, 0, 0);
            acc[t] = __builtin_amdgcn_mfma_f32_16x16x32_bf16(al, bh[s], acc[t], 0, 0, 0);
            acc[t] = __builtin_amdgcn_mfma_f32_16x16x32_bf16(ah, bl[s], acc[t], 0, 0, 0);
        }
    }
    __syncthreads();   // all [h|S] reads done

    // stage-2 B regs (U2, K=128)
    short8v b2h[4], b2l[4];
    {
        size_t wbase = (size_t)col * 128 + (size_t)(g * 8);
#pragma unroll
        for (int s = 0; s < 4; ++s) {
            b2h[s] = *(const short8v*)(W2th + wbase + s * 32);
            b2l[s] = *(const short8v*)(W2tl + wbase + s * 32);
        }
    }

    // U epilogue -> LDS tile (stride 256B, swizzled)
    {
        const float bb = b1[col];
        const float bd = bdeg[col];
#pragma unroll
        for (int t = 0; t < 4; ++t) {
#pragma unroll
            for (int i = 0; i < 4; ++i) {
                int lrow = t * 16 + g * 4 + i;
                int grow = rb + lrow;
                float dg = (grow < nrows) ? deg[grow] : 0.f;
                float v = acc[t][i] + bb + dg * bd;
                v = fmaxf(v, 0.f);
                us uh = f2bf(v);
                us ul = f2bf(v - bf2f(uh));
                int byte = lrow * 256 + ((col * 2) ^ ((lrow & 7) << 4));
                *(us*)((char*)As_h + byte) = uh;
                *(us*)((char*)As_l + byte) = ul;
            }
        }
    }
    __syncthreads();

    // stage 2: hout = relu(U @ U2 + b2)
    f32x4 acc2[4];
#pragma unroll
    for (int t = 0; t < 4; ++t) acc2[t] = (f32x4){0.f, 0.f, 0.f, 0.f};
#pragma unroll
    for (int s = 0; s < 4; ++s) {
#pragma unroll
        for (int t = 0; t < 4; ++t) {
            int row = t * 16 + r;
            int boff = row * 256 + (((s * 64) + g * 16) ^ ((row & 7) << 4));
            short8v ah = *(const short8v*)((const char*)As_h + boff);
            short8v al = *(const short8v*)((const char*)As_l + boff);
            acc2[t] = __builtin_amdgcn_mfma_f32_16x16x32_bf16(ah, b2h[s], acc2[t], 0, 0, 0);
            acc2[t] = __builtin_amdgcn_mfma_f32_16x16x32_bf16(al, b2h[s], acc2[t], 0, 0, 0);
            acc2[t] = __builtin_amdgcn_mfma_f32_16x16x32_bf16(ah, b2l[s], acc2[t], 0, 0, 0);
        }
    }
    if (!DOPQ) {
        const float bb2 = b2[col];
#pragma unroll
        for (int t = 0; t < 4; ++t) {
#pragma unroll
            for (int i = 0; i < 4; ++i) {
                int row = rb + t * 16 + g * 4 + i;
                if (row >= nrows) continue;
                float v = fmaxf(acc2[t][i] + bb2, 0.f);
                size_t o = (size_t)row * HD + col;
                us hh = f2bf(v);
                out_h[o] = hh;
                out_l[o] = f2bf(v - bf2f(hh));
            }
        }
        return;
    }

    __syncthreads();   // all U-tile reads done; safe to overwrite with h tile
    // hout epilogue -> global pair + LDS tile
    {
        const float bb2 = b2[col];
#pragma unroll
        for (int t = 0; t < 4; ++t) {
#pragma unroll
            for (int i = 0; i < 4; ++i) {
                int lrow = t * 16 + g * 4 + i;
                int grow = rb + lrow;
                float v = fmaxf(acc2[t][i] + bb2, 0.f);
                us hh = f2bf(v);
                us hl2 = f2bf(v - bf2f(hh));
                if (grow < nrows) {
                    size_t o = (size_t)grow * HD + col;
                    out_h[o] = hh; out_l[o] = hl2;
                }
                int byte = lrow * 256 + ((col * 2) ^ ((lrow & 7) << 4));
                *(us*)((char*)As_h + byte) = hh;
                *(us*)((char*)As_l + byte) = hl2;
            }
        }
    }
    __syncthreads();

    // stage 3: [P|Q] = hout @ [Wa|Wb] of NEXT layer
    short8v bPh[4], bPl[4], bQh[4], bQl[4];
    {
        size_t baseP = (size_t)col * 128 + (size_t)(g * 8);
        size_t baseQ = (size_t)(col + 128) * 128 + (size_t)(g * 8);
#pragma unroll
        for (int s = 0; s < 4; ++s) {
            bPh[s] = *(const short8v*)(wpqh + baseP + s * 32);
            bPl[s] = *(const short8v*)(wpql + baseP + s * 32);
            bQh[s] = *(const short8v*)(wpqh + baseQ + s * 32);
            bQl[s] = *(const short8v*)(wpql + baseQ + s * 32);
        }
    }
    f32x4 accP[4], accQ[4];
#pragma unroll
    for (int t = 0; t < 4; ++t) {
        accP[t] = (f32x4){0.f, 0.f, 0.f, 0.f};
        accQ[t] = (f32x4){0.f, 0.f, 0.f, 0.f};
    }
#pragma unroll
    for (int s = 0; s < 4; ++s) {
#pragma unroll
        for (int t = 0; t < 4; ++t) {
            int row = t * 16 + r;
            int boff = row * 256 + (((s * 64) + g * 16) ^ ((row & 7) << 4));
            short8v ah = *(const short8v*)((const char*)As_h + boff);
            short8v al = *(const short8v*)((const char*)As_l + boff);
            accP[t] = __builtin_amdgcn_mfma_f32_16x16x32_bf16(ah, bPh[s], accP[t], 0, 0, 0);
            accP[t] = __builtin_amdgcn_mfma_f32_16x16x32_bf16(al, bPh[s], accP[t], 0, 0, 0);
            accP[t] = __builtin_amdgcn_mfma_f32_16x16x32_bf16(ah, bPl[s], accP[t], 0, 0, 0);
            accQ[t] = __builtin_amdgcn_mfma_f32_16x16x32_bf16(ah, bQh[s], accQ[t], 0, 0, 0);
            accQ[t] = __builtin_amdgcn_mfma_f32_16x16x32_bf16(al, bQh[s], accQ[t], 0, 0, 0);
            accQ[t] = __builtin_amdgcn_mfma_f32_16x16x32_bf16(ah, bQl[s], accQ[t], 0, 0, 0);
        }
    }
    {
        const float bbP = b1msg[col];
#pragma unroll
        for (int t = 0; t < 4; ++t) {
#pragma unroll
            for (int i = 0; i < 4; ++i) {
                int row = rb + t * 16 + g * 4 + i;
                if (row >= nrows) continue;
                size_t o = (size_t)row * HD + col;
                Pb[o] = accP[t][i] + bbP;
                Qb[o] = accQ[t][i];
            }
        }
    }
}

// ---------------------------------------------------------------------------
// Conversions
// ---------------------------------------------------------------------------
__global__ void k_cvtA(const float* __restrict__ src,
                       us* __restrict__ dh, us* __restrict__ dl, long n)
{
    long i = (long)blockIdx.x * blockDim.x + threadIdx.x;
    if (i >= n) return;
    float v = src[i];
    us h = f2bf(v);
    dh[i] = h;
    dl[i] = f2bf(v - bf2f(h));
}

__global__ void k_cvtW(const float* __restrict__ src, long sstride, int K,
                       us* __restrict__ dh, us* __restrict__ dl, long dstride)
{
    int l = blockIdx.y;
    int idx = blockIdx.x * 256 + threadIdx.x;
    if (idx >= K * 128) return;
    int k = idx >> 7, j = idx & 127;
    float v = src[(size_t)l * sstride + (size_t)k * 128 + j];
    us h = f2bf(v);
    size_t o = (size_t)l * dstride + (size_t)j * K + k;
    dh[o] = h;
    dl[o] = f2bf(v - bf2f(h));
}

__global__ void k_cvtW2(const float* __restrict__ srcA, long strideA,
                        const float* __restrict__ srcB, long strideB,
                        int K1s, int K,
                        us* __restrict__ dh, us* __restrict__ dl, long dstride)
{
    int l = blockIdx.y;
    int idx = blockIdx.x * 256 + threadIdx.x;
    if (idx >= K * 128) return;
    int k = idx >> 7, j = idx & 127;
    float v = (k < K1s)
        ? srcA[(size_t)l * strideA + (size_t)k * 128 + j]
        : srcB[(size_t)l * strideB + (size_t)(k - K1s) * 128 + j];
    us h = f2bf(v);
    size_t o = (size_t)l * dstride + (size_t)j * K + k;
    dh[o] = h;
    dl[o] = f2bf(v - bf2f(h));
}

// ---------------------------------------------------------------------------
// CSR build: deg+hist -> 3-phase parallel scan -> scatter (fused ea permute)
// ---------------------------------------------------------------------------
__global__ void k_deghist(const int* __restrict__ dst, int* __restrict__ degi, int E,
                          const int* __restrict__ batch, int* __restrict__ gcnt, int N)
{
    int i = blockIdx.x * blockDim.x + threadIdx.x;
    if (i < E) atomicAdd(&degi[dst[i]], 1);
    if (i < N) atomicAdd(&gcnt[batch[i]], 1);
}

__global__ __launch_bounds__(256) void k_scan1(const int* __restrict__ degi,
                                               int* __restrict__ thrpre,
                                               int* __restrict__ bsum, int N)
{
    __shared__ int sc[256];
    const int t = threadIdx.x, b = blockIdx.x;
    int i0 = b * SCB + t * 8;
    int s = 0;
#pragma unroll
    for (int q = 0; q < 8; ++q) {
        int i = i0 + q;
        if (i < N) s += degi[i];
    }
    sc[t] = s;
    __syncthreads();
    for (int o = 1; o < 256; o <<= 1) {
        int v = (t >= o) ? sc[t - o] : 0;
        __syncthreads();
        sc[t] += v;
        __syncthreads();
    }
    thrpre[b * 256 + t] = sc[t] - s;
    if (t == 255) bsum[b] = sc[255];
}

__global__ void k_scan2(const int* __restrict__ bsum, int* __restrict__ boff, int nb)
{
    if (threadIdx.x == 0 && blockIdx.x == 0) {
        int run = 0;
        for (int b = 0; b < nb; ++b) { boff[b] = run; run += bsum[b]; }
    }
}

__global__ __launch_bounds__(256) void k_scan3(
    const int* __restrict__ degi, const int* __restrict__ thrpre,
    const int* __restrict__ boff,
    int* __restrict__ rowptr, int* __restrict__ cursor,
    float* __restrict__ degf, int N, int E)
{
    const int t = threadIdx.x, b = blockIdx.x;
    int run = boff[b] + thrpre[b * 256 + t];
    int i0 = b * SCB + t * 8;
#pragma unroll
    for (int q = 0; q < 8; ++q) {
        int i = i0 + q;
        if (i < N) {
            int d = degi[i];
            rowptr[i] = run;
            cursor[i] = run;
            degf[i] = (float)d;
            run += d;
        }
    }
    if (b == 0 && t == 0) rowptr[N] = E;
}

__global__ void k_scatter(const int* __restrict__ dst, const int* __restrict__ src,
                          int* __restrict__ cursor,
                          const float* __restrict__ ea,
                          int* __restrict__ csr_src, int* __restrict__ csr_eid,
                          float* __restrict__ ea_p, int E)
{
    int e = blockIdx.x * blockDim.x + threadIdx.x;
    if (e >= E) return;
    int d = dst[e];
    int pos = atomicAdd(&cursor[d], 1);
    csr_src[pos] = src[e];
    if (ea_p) {
        const float4* s4 = (const float4*)&ea[(size_t)e * 16];
        float4* d4 = (float4*)&ea_p[(size_t)pos * 16];
        d4[0] = s4[0]; d4[1] = s4[1]; d4[2] = s4[2]; d4[3] = s4[3];
    } else {
        csr_eid[pos] = e;
    }
}

// ---------------------------------------------------------------------------
// Weight folds: fold = W2 @ U1b ; bvec2 = b2 @ U1b
// ---------------------------------------------------------------------------
__global__ __launch_bounds__(256) void k_foldW(
    const float* __restrict__ msg_W2, const float* __restrict__ upd_W1,
    float* __restrict__ fold)
{
    int l = blockIdx.x >> 3, rb = blockIdx.x & 7;
    const float* W2  = msg_W2 + (size_t)l * HD * HD;
    const float* U1b = upd_W1 + (size_t)l * 256 * HD + (size_t)HD * HD;
    float* Wout = fold + (size_t)l * HD * HD;
    int j = threadIdx.x & 127;
    int rh = threadIdx.x >> 7;
    int r0 = rb * 16 + rh * 8;
    float acc[8] = {0.f,0.f,0.f,0.f,0.f,0.f,0.f,0.f};
    for (int k = 0; k < HD; ++k) {
        float u = U1b[(size_t)k * HD + j];
#pragma unroll
        for (int rr = 0; rr < 8; ++rr)
            acc[rr] = fmaf(W2[(size_t)(r0 + rr) * HD + k], u, acc[rr]);
    }
#pragma unroll
    for (int rr = 0; rr < 8; ++rr)
        Wout[(size_t)(r0 + rr) * HD + j] = acc[rr];
}

__global__ __launch_bounds__(128) void k_foldb(
    const float* __restrict__ msg_b2, const float* __restrict__ upd_W1,
    float* __restrict__ bvec2)
{
    int l = blockIdx.x, j = threadIdx.x;
    const float* U1b = upd_W1 + (size_t)l * 256 * HD + (size_t)HD * HD;
    const float* b2 = msg_b2 + (size_t)l * HD;
    float acc = 0.f;
    for (int k = 0; k < HD; ++k) acc = fmaf(b2[k], U1b[(size_t)k * HD + j], acc);
    bvec2[(size_t)l * HD + j] = acc;
}

// ---------------------------------------------------------------------------
// Edge gather: S[n] = sum_{e:dst=n} relu(P[n] + Q[src] + ea@Wc)
// ONE WAVE PER BLOCK (64 thr): each node retires independently (no max-of-4
// block coupling). 2 dims/lane, 16-edge clamped batch, readlane indices.
// ---------------------------------------------------------------------------
#define EB 16
template<bool PERM>
__global__ __launch_bounds__(64) void k_edge(
    const float* __restrict__ P, const float* __restrict__ Q,
    const float* __restrict__ EA,
    const int* __restrict__ rowptr,
    const int* __restrict__ csr_src, const int* __restrict__ csr_eid,
    const float* __restrict__ W1c,
    us* __restrict__ Sh, us* __restrict__ Sl, int N)
{
    const int lane = threadIdx.x & 63;
    const int node = __builtin_amdgcn_readfirstlane(blockIdx.x);
    if (node >= N) return;
    float wA[16], wB[16];
#pragma unroll
    for (int k = 0; k < 16; ++k) {
        wA[k] = W1c[k * HD + lane];
        wB[k] = W1c[k * HD + 64 + lane];
    }
    const int beg = __builtin_amdgcn_readfirstlane(rowptr[node]);
    const int end = __builtin_amdgcn_readfirstlane(rowptr[node + 1]);
    const float pA = P[(size_t)node * HD + lane];
    const float pB = P[(size_t)node * HD + 64 + lane];
    float accA = 0.f, accB = 0.f;

    for (int i = beg; i < end; i += EB) {
        int myi = i + (lane & 15);
        myi = (myi < end) ? myi : (end - 1);
        int myidx = PERM ? myi : csr_eid[myi];
        int mysrc = csr_src[myi];
        int sv[EB], ei[EB];
#pragma unroll
        for (int r = 0; r < EB; ++r) {
            sv[r] = __builtin_amdgcn_readlane(mysrc, r);
            ei[r] = PERM ? 0 : __builtin_amdgcn_readlane(myidx, r);
        }
        float qA[EB], qB[EB];
#pragma unroll
        for (int r = 0; r < EB; ++r) {
            qA[r] = Q[(size_t)sv[r] * HD + lane];
            qB[r] = Q[(size_t)sv[r] * HD + 64 + lane];
        }
#pragma unroll
        for (int r = 0; r < EB; ++r) {
            int ii = i + r; ii = (ii < end) ? ii : (end - 1);
            const float4* Ev = PERM ? (const float4*)&EA[(size_t)ii * 16]
                                    : (const float4*)&EA[(size_t)ei[r] * 16];
            float4 v0 = Ev[0], v1 = Ev[1], v2 = Ev[2], v3 = Ev[3];
            float tA = pA + qA[r], tB = pB + qB[r];
            tA = fmaf(v0.x, wA[0],  tA); tB = fmaf(v0.x, wB[0],  tB);
            tA = fmaf(v0.y, wA[1],  tA); tB = fmaf(v0.y, wB[1],  tB);
            tA = fmaf(v0.z, wA[2],  tA); tB = fmaf(v0.z, wB[2],  tB);
            tA = fmaf(v0.w, wA[3],  tA); tB = fmaf(v0.w, wB[3],  tB);
            tA = fmaf(v1.x, wA[4],  tA); tB = fmaf(v1.x, wB[4],  tB);
            tA = fmaf(v1.y, wA[5],  tA); tB = fmaf(v1.y, wB[5],  tB);
            tA = fmaf(v1.z, wA[6],  tA); tB = fmaf(v1.z, wB[6],  tB);
            tA = fmaf(v1.w, wA[7],  tA); tB = fmaf(v1.w, wB[7],  tB);
            tA = fmaf(v2.x, wA[8],  tA); tB = fmaf(v2.x, wB[8],  tB);
            tA = fmaf(v2.y, wA[9],  tA); tB = fmaf(v2.y, wB[9],  tB);
            tA = fmaf(v2.z, wA[10], tA); tB = fmaf(v2.z, wB[10], tB);
            tA = fmaf(v2.w, wA[11], tA); tB = fmaf(v2.w, wB[11], tB);
            tA = fmaf(v3.x, wA[12], tA); tB = fmaf(v3.x, wB[12], tB);
            tA = fmaf(v3.y, wA[13], tA); tB = fmaf(v3.y, wB[13], tB);
            tA = fmaf(v3.z, wA[14], tA); tB = fmaf(v3.z, wB[14], tB);
            tA = fmaf(v3.w, wA[15], tA); tB = fmaf(v3.w, wB[15], tB);
            bool ok = (i + r) < end;
            accA += ok ? fmaxf(tA, 0.f) : 0.f;
            accB += ok ? fmaxf(tB, 0.f) : 0.f;
        }
    }
    size_t oA = (size_t)node * HD + lane;
    size_t oB = oA + 64;
    us hA = f2bf(accA);
    us hB = f2bf(accB);
    Sh[oA] = hA; Sl[oA] = f2bf(accA - bf2f(hA));
    Sh[oB] = hB; Sl[oB] = f2bf(accB - bf2f(hB));
}

// ---------------------------------------------------------------------------
// Pool (segment mean/max over sorted batch) from bf16 hi/lo h; then classifier.
// ---------------------------------------------------------------------------
__global__ __launch_bounds__(256) void k_pool2(
    const us* __restrict__ hh, const us* __restrict__ hl,
    const int* __restrict__ batch,
    float* __restrict__ gsum, unsigned int* __restrict__ gmax, int N)
{
    int nchunk = (N + gridDim.x - 1) / gridDim.x;
    int n0 = blockIdx.x * nchunk;
    int n1 = n0 + nchunk; if (n1 > N) n1 = N;
    int j = threadIdx.x & 127;
    int half = threadIdx.x >> 7;
    float s = 0.f, m = 0.f; int gcur = -1;
    for (int n = n0 + half; n < n1; n += 2) {
        int g = batch[n];
        if (g != gcur) {
            if (gcur >= 0) {
                atomicAdd(&gsum[(size_t)gcur * HD + j], s);
                atomicMax(&gmax[(size_t)gcur * HD + j], __float_as_uint(m));
            }
            gcur = g; s = 0.f; m = 0.f;
        }
        size_t o = (size_t)n * HD + j;
        float v = bf2f(hh[o]) + bf2f(hl[o]);
        s += v; m = fmaxf(m, v);
    }
    if (gcur >= 0) {
        atomicAdd(&gsum[(size_t)gcur * HD + j], s);
        atomicMax(&gmax[(size_t)gcur * HD + j], __float_as_uint(m));
    }
}

__global__ __launch_bounds__(128) void k_cls(
    const float* __restrict__ gsum, const float* __restrict__ gmax,
    const int* __restrict__ gcnt,
    const float* __restrict__ W1, const float* __restrict__ b1,
    const float* __restrict__ W2, const float* __restrict__ b2,
    const float* __restrict__ W3, const float* __restrict__ b3,
    float* __restrict__ out)
{
    __shared__ float rep[256];
    __shared__ float z1[128];
    __shared__ float z2[64];
    const int g = blockIdx.x;
    const int j = threadIdx.x;
    float cntf = (float)gcnt[g];
    rep[j]       = gsum[(size_t)g * HD + j] / fmaxf(cntf, 1.f);
    rep[128 + j] = gmax[(size_t)g * HD + j];
    __syncthreads();
    float a = 0.f;
    for (int k = 0; k < 256; ++k) a = fmaf(rep[k], W1[(size_t)k * 128 + j], a);
    z1[j] = fmaxf(a + b1[j], 0.f);
    __syncthreads();
    if (j < 64) {
        float b = 0.f;
        for (int k = 0; k < 128; ++k) b = fmaf(z1[k], W2[(size_t)k * 64 + j], b);
        z2[j] = fmaxf(b + b2[j], 0.f);
    }
    __syncthreads();
    if (j < 2) {
        float c = 0.f;
        for (int k = 0; k < 64; ++k) c = fmaf(z2[k], W3[(size_t)k * 2 + j], c);
        out[(size_t)g * 2 + j] = c + b3[j];
    }
}

extern "C" void kernel_launch(void* const* d_in, const int* in_sizes, int n_in,
                              void* d_out, int out_size, void* d_ws, size_t ws_size,
                              hipStream_t stream) {
    const float* x      = (const float*)d_in[0];
    const float* ea     = (const float*)d_in[1];
    const int*   ei     = (const int*)d_in[2];
    const int*   batch  = (const int*)d_in[3];
    const float* emb_W  = (const float*)d_in[4];
    const float* emb_b  = (const float*)d_in[5];
    const float* msg_W1 = (const float*)d_in[6];
    const float* msg_b1 = (const float*)d_in[7];
    const float* msg_W2 = (const float*)d_in[8];
    const float* msg_b2 = (const float*)d_in[9];
    const float* upd_W1 = (const float*)d_in[10];
    const float* upd_b1 = (const float*)d_in[11];
    const float* upd_W2 = (const float*)d_in[12];
    const float* upd_b2 = (const float*)d_in[13];
    const float* cW1 = (const float*)d_in[14];
    const float* cb1 = (const float*)d_in[15];
    const float* cW2 = (const float*)d_in[16];
    const float* cb2 = (const float*)d_in[17];
    const float* cW3 = (const float*)d_in[18];
    const float* cb3 = (const float*)d_in[19];

    const int N = in_sizes[0] / 64;
    const int E = in_sizes[1] / 16;
    const int G = 256, L = 3;
    const int* src = ei;
    const int* dst = ei + E;
    const int nb = (N + SCB - 1) / SCB;

    char* w = (char*)d_ws;
    size_t off = 0;
    auto alloc = [&](size_t bytes) -> void* {
        void* p = w + off;
        off += (bytes + 255) & ~(size_t)255;
        return p;
    };
    float* Pb  = (float*)alloc((size_t)N * HD * 4);  // P fp32
    float* Qb  = (float*)alloc((size_t)N * HD * 4);  // Q fp32
    us* S_h = (us*)alloc((size_t)N * HD * 2);        // S hi; aliased as x_h
    us* S_l = (us*)alloc((size_t)N * HD * 2);        // S lo; aliased as x_l
    us* h_h = (us*)alloc((size_t)N * HD * 2);
    us* h_l = (us*)alloc((size_t)N * HD * 2);
    us* x_h = S_h;                                   // alias: x pair over S pair
    us* x_l = S_l;
    float* fold  = (float*)alloc((size_t)L * HD * HD * 4);
    float* bvec2 = (float*)alloc((size_t)L * HD * 4);
    us* embt_h = (us*)alloc((size_t)128 * 64 * 2);
    us* embt_l = (us*)alloc((size_t)128 * 64 * 2);
    us* WPQt_h = (us*)alloc((size_t)L * 256 * 128 * 2);  // [256 j][128 k]
    us* WPQt_l = (us*)alloc((size_t)L * 256 * 128 * 2);
    us* Wcbt_h = (us*)alloc((size_t)L * 128 * 256 * 2);  // [128 j][256 k]
    us* Wcbt_l = (us*)alloc((size_t)L * 128 * 256 * 2);
    us* U2t_h  = (us*)alloc((size_t)L * 128 * 128 * 2);
    us* U2t_l  = (us*)alloc((size_t)L * 128 * 128 * 2);
    int*   degi   = (int*)alloc((size_t)N * 4);
    float* degf   = (float*)alloc((size_t)N * 4);
    int*   rowptr = (int*)alloc((size_t)(N + 1) * 4);
    int*   cursor = (int*)alloc((size_t)N * 4);
    int*   thrpre = (int*)alloc((size_t)nb * 256 * 4);
    int*   bsum   = (int*)alloc((size_t)(nb + 1) * 4);
    int*   boff   = (int*)alloc((size_t)(nb + 1) * 4);
    int*   gcnt   = (int*)alloc(256 * 4);
    float* gsum   = (float*)alloc((size_t)G * HD * 4);
    float* gmax   = (float*)alloc((size_t)G * HD * 4);
    int*   csr_src = (int*)alloc((size_t)E * 4);
    int*   csr_eid = (int*)alloc((size_t)E * 4);
    float* ea_p = nullptr;
    if (ws_size && off + (size_t)E * 16 * 4 + 256 <= ws_size)
        ea_p = (float*)alloc((size_t)E * 16 * 4);
    (void)n_in; (void)out_size;

    hipMemsetAsync(degi, 0, (size_t)N * 4, stream);
    hipMemsetAsync(gcnt, 0, 256 * 4, stream);
    hipMemsetAsync(gsum, 0, (size_t)G * HD * 4, stream);
    hipMemsetAsync(gmax, 0, (size_t)G * HD * 4, stream);

    // ---- CSR build (parallel scan; scatter fuses ea permutation) ----
    int mEN = (E > N ? E : N);
    k_deghist<<<(mEN + 255) / 256, 256, 0, stream>>>(dst, degi, E, batch, gcnt, N);
    k_scan1<<<nb, 256, 0, stream>>>(degi, thrpre, bsum, N);
    k_scan2<<<1, 64, 0, stream>>>(bsum, boff, nb);
    k_scan3<<<nb, 256, 0, stream>>>(degi, thrpre, boff, rowptr, cursor, degf, N, E);
    k_scatter<<<(E + 255) / 256, 256, 0, stream>>>(dst, src, cursor, ea,
                                                   csr_src, csr_eid, ea_p, E);

    // ---- weight folds + conversions ----
    k_foldW<<<L * 8, 256, 0, stream>>>(msg_W2, upd_W1, fold);
    k_foldb<<<L, 128, 0, stream>>>(msg_b2, upd_W1, bvec2);

    k_cvtA<<<(int)(((long)N * 64 + 255) / 256), 256, 0, stream>>>(x, x_h, x_l, (long)N * 64);
    k_cvtW<<<dim3(32, 1), 256, 0, stream>>>(emb_W, 0, 64, embt_h, embt_l, 0);
    k_cvtW<<<dim3(64, L), 256, 0, stream>>>(msg_W1, 272 * 128, 128,
                                            WPQt_h, WPQt_l, 256 * 128);
    k_cvtW<<<dim3(64, L), 256, 0, stream>>>(msg_W1 + 128 * 128, 272 * 128, 128,
                                            WPQt_h + 128 * 128, WPQt_l + 128 * 128,
                                            256 * 128);
    k_cvtW2<<<dim3(128, L), 256, 0, stream>>>(upd_W1, 256 * 128, fold, 128 * 128,
                                              128, 256, Wcbt_h, Wcbt_l, 128 * 256);
    k_cvtW<<<dim3(64, L), 256, 0, stream>>>(upd_W2, 128 * 128, 128,
                                            U2t_h, U2t_l, 128 * 128);

    const int gb = (N + 63) / 64;
    // ---- fused embed + layer-0 PQ ----
    k_embpq<<<gb, 512, 0, stream>>>(x_h, x_l, embt_h, embt_l, emb_b,
                                    WPQt_h, WPQt_l, msg_b1,
                                    h_h, h_l, Pb, Qb, N);

    for (int l = 0; l < L; ++l) {
        const float* W1 = msg_W1 + (size_t)l * 272 * HD;
        // S[n] = sum_in relu(P[n] + Q[src] + ea@Wc) -> bf16 pair
        if (ea_p)
            k_edge<true><<<N, 64, 0, stream>>>(Pb, Qb, ea_p, rowptr,
                                               csr_src, nullptr,
                                               W1 + 256 * HD, S_h, S_l, N);
        else
            k_edge<false><<<N, 64, 0, stream>>>(Pb, Qb, ea, rowptr,
                                                csr_src, csr_eid,
                                                W1 + 256 * HD, S_h, S_l, N);
        // fused update (+ next-layer PQ for l < L-1)
        if (l < L - 1)
            k_updpq<true><<<gb, 512, 0, stream>>>(
                h_h, h_l, S_h, S_l,
                Wcbt_h + (size_t)l * 128 * 256, Wcbt_l + (size_t)l * 128 * 256,
                upd_b1 + (size_t)l * HD, bvec2 + (size_t)l * HD, degf,
                U2t_h + (size_t)l * 128 * 128, U2t_l + (size_t)l * 128 * 128,
                upd_b2 + (size_t)l * HD,
                WPQt_h + (size_t)(l + 1) * 256 * 128,
                WPQt_l + (size_t)(l + 1) * 256 * 128,
                msg_b1 + (size_t)(l + 1) * HD,
                h_h, h_l, Pb, Qb, N);
        else
            k_updpq<false><<<gb, 512, 0, stream>>>(
                h_h, h_l, S_h, S_l,
                Wcbt_h + (size_t)l * 128 * 256, Wcbt_l + (size_t)l * 128 * 256,
                upd_b1 + (size_t)l * HD, bvec2 + (size_t)l * HD, degf,
                U2t_h + (size_t)l * 128 * 128, U2t_l + (size_t)l * 128 * 128,
                upd_b2 + (size_t)l * HD,
                nullptr, nullptr, nullptr,
                h_h, h_l, nullptr, nullptr, N);
    }

    k_pool2<<<1024, 256, 0, stream>>>(h_h, h_l, batch, gsum, (unsigned int*)gmax, N);
    k_cls<<<G, 128, 0, stream>>>(gsum, gmax, gcnt, cW1, cb1, cW2, cb2, cW3, cb3,
                                 (float*)d_out);
}